// Round 1
// baseline (452.245 us; speedup 1.0000x reference)
//
#include <hip/hip_runtime.h>
#include <math.h>

#define F_NUM 8
#define N_AT 2048
#define E_EDGE 32768
#define FE (F_NUM*E_EDGE)   // 262144 base edges
#define FN (F_NUM*N_AT)     // 16384 atoms
#define PI_F 3.14159265358979f

// ---------------- edge geometry: basis, dbasis/dr, unit vectors, degree histogram ----------------
__global__ __launch_bounds__(256) void k_edges(
    const float* __restrict__ pos, const int* __restrict__ eidx,
    const float* __restrict__ cell, const int* __restrict__ co_p,
    float* __restrict__ basis, float* __restrict__ dbasis,
    float* __restrict__ unit, int* __restrict__ deg)
{
    int k = blockIdx.x * 256 + threadIdx.x;
    if (k >= FE) return;
    int f = k >> 15;            // E = 32768
    int e = k & (E_EDGE - 1);
    int a = eidx[f * 2 * E_EDGE + e] + f * N_AT;
    int b = eidx[f * 2 * E_EDGE + E_EDGE + e] + f * N_AT;
    float co = (float)co_p[0];

    float vec[3];
#pragma unroll
    for (int d = 0; d < 3; d++) {
        float v  = pos[3 * b + d] - pos[3 * a + d];
        float cl = cell[3 * f + d];
        float sh = cl * ((v < -co ? 1.f : 0.f) - (v > co ? 1.f : 0.f));
        vec[d] = v + sh;
    }
    float r2   = vec[0]*vec[0] + vec[1]*vec[1] + vec[2]*vec[2] + 1e-12f;
    float r    = sqrtf(r2);
    float rinv = 1.f / r;
    unit[3*k+0] = vec[0] * rinv;
    unit[3*k+1] = vec[1] * rinv;
    unit[3*k+2] = vec[2] * rinv;

    float x = r * (1.f / 6.f);           // R_MAX = 6
    float env = 0.f, denv = 0.f;
    if (x < 1.f) {
        float x2 = x*x, x3 = x2*x, x5 = x2*x3, x6 = x5*x, x7 = x6*x, x8 = x7*x;
        env  = 1.f - 28.f*x6 + 48.f*x7 - 21.f*x8;
        denv = -168.f*x5 + 336.f*x6 - 168.f*x7;   // d env / d x
    }
    float s1, c1;
    sincosf(PI_F * x, &s1, &c1);
    float sn = s1, cn = c1;
    const float C0 = 0.57735026919f;     // sqrt(2/6)
    float bs[8], db[8];
#pragma unroll
    for (int n = 1; n <= 8; n++) {
        float kn  = (float)n * PI_F * (1.f / 6.f);
        float bes = C0 * sn * rinv;
        bs[n-1] = bes * env;
        // d/dr [C0 sin(n pi x)/r * env(x)]
        db[n-1] = C0 * rinv * (kn * cn - sn * rinv) * env + bes * denv * (1.f / 6.f);
        float sn2 = sn * c1 + cn * s1;
        float cn2 = cn * c1 - sn * s1;
        sn = sn2; cn = cn2;
    }
    float4* bp = reinterpret_cast<float4*>(basis  + (size_t)k * 8);
    float4* dp = reinterpret_cast<float4*>(dbasis + (size_t)k * 8);
    bp[0] = make_float4(bs[0], bs[1], bs[2], bs[3]);
    bp[1] = make_float4(bs[4], bs[5], bs[6], bs[7]);
    dp[0] = make_float4(db[0], db[1], db[2], db[3]);
    dp[1] = make_float4(db[4], db[5], db[6], db[7]);

    atomicAdd(&deg[a], 1);
    atomicAdd(&deg[b], 1);
}

// ---------------- exclusive scan of degrees (FN = 16384 = 1024 threads x 16) ----------------
__global__ __launch_bounds__(1024) void k_scan(const int* __restrict__ deg, int* __restrict__ offs)
{
    __shared__ int sm[1024];
    int t = threadIdx.x;
    int base = t * 16;
    int loc[16];
    int s = 0;
#pragma unroll
    for (int i = 0; i < 16; i++) { loc[i] = s; s += deg[base + i]; }
    sm[t] = s;
    __syncthreads();
    for (int d = 1; d < 1024; d <<= 1) {
        int v = (t >= d) ? sm[t - d] : 0;
        __syncthreads();
        sm[t] += v;
        __syncthreads();
    }
    int pre = (t == 0) ? 0 : sm[t - 1];
#pragma unroll
    for (int i = 0; i < 16; i++) offs[base + i] = pre + loc[i];
    if (t == 1023) offs[FN] = sm[1023];
}

// ---------------- scatter incidences into CSR ----------------
__global__ __launch_bounds__(256) void k_scatter(
    const int* __restrict__ eidx, const int* __restrict__ offs, int* __restrict__ cur,
    int* __restrict__ inc_k, int* __restrict__ inc_nb)
{
    int k = blockIdx.x * 256 + threadIdx.x;
    if (k >= FE) return;
    int f = k >> 15;
    int e = k & (E_EDGE - 1);
    int a = eidx[f * 2 * E_EDGE + e] + f * N_AT;
    int b = eidx[f * 2 * E_EDGE + E_EDGE + e] + f * N_AT;
    int pa = atomicAdd(&cur[a], 1);
    int ia = offs[a] + pa;
    inc_k[ia] = k; inc_nb[ia] = (b << 1);        // n==a (original src): dir bit 0
    int pb = atomicAdd(&cur[b], 1);
    int ib = offs[b] + pb;
    inc_k[ib] = k; inc_nb[ib] = (a << 1) | 1;    // n==b (original dst): dir bit 1
}

// ---------------- embedding ----------------
__global__ __launch_bounds__(256) void k_embed(
    const int* __restrict__ at, const float* __restrict__ W_embed, float* __restrict__ s0)
{
    int gid = blockIdx.x * 256 + threadIdx.x;   // FN*32
    int n = gid >> 5, c = gid & 31;
    s0[gid] = W_embed[at[n] * 32 + c];
}

// ---------------- forward layer: A[n,c] = sum_inc R[k,c]*s[u,c]; s' = s + A @ Wmix ----------------
__global__ __launch_bounds__(256) void k_layer(
    const float* __restrict__ sl, float* __restrict__ slp1,
    const float* __restrict__ basis, const int* __restrict__ offs,
    const int* __restrict__ inc_k, const int* __restrict__ inc_nb,
    const float* __restrict__ Wrad_l, const float* __restrict__ Wmix_l)
{
    __shared__ float wmix[1024];
    __shared__ float Ash[8][32];
    int t = threadIdx.x;
    for (int i = t; i < 1024; i += 256) wmix[i] = Wmix_l[i];
    int n = blockIdx.x * 8 + (t >> 5);
    int c = t & 31;
    float wr0[8];
#pragma unroll
    for (int bb = 0; bb < 8; bb++) wr0[bb] = Wrad_l[bb * 128 + c * 4];

    float A = 0.f;
    int j1 = offs[n + 1];
    for (int j = offs[n]; j < j1; j++) {
        int k = inc_k[j];
        int u = inc_nb[j] >> 1;
        const float4* bp = reinterpret_cast<const float4*>(basis + (size_t)k * 8);
        float4 b0 = bp[0], b1 = bp[1];
        float R = b0.x*wr0[0] + b0.y*wr0[1] + b0.z*wr0[2] + b0.w*wr0[3]
                + b1.x*wr0[4] + b1.y*wr0[5] + b1.z*wr0[6] + b1.w*wr0[7];
        A += R * sl[u * 32 + c];
    }
    Ash[t >> 5][c] = A;
    __syncthreads();
    float acc = sl[n * 32 + c];
    const float* Arow = Ash[t >> 5];
#pragma unroll
    for (int cc = 0; cc < 32; cc++) acc += Arow[cc] * wmix[cc * 32 + c];
    slp1[n * 32 + c] = acc;
}

// ---------------- init barS3 = w_out (uniform over atoms) ----------------
__global__ __launch_bounds__(256) void k_initbars(const float* __restrict__ w_out, float* __restrict__ barS)
{
    int gid = blockIdx.x * 256 + threadIdx.x;
    barS[gid] = w_out[gid & 31];
}

// ---------------- barA[n,c] = sum_d barS_next[n,d] * Wmix[c,d] ----------------
__global__ __launch_bounds__(256) void k_barA(
    const float* __restrict__ barS_next, const float* __restrict__ Wmix_l, float* __restrict__ barA)
{
    __shared__ float wmixT[1024];   // [d][c]
    __shared__ float Bsh[8][32];
    int t = threadIdx.x;
    for (int i = t; i < 1024; i += 256) {
        int cc = i >> 5, dd = i & 31;
        wmixT[dd * 32 + cc] = Wmix_l[i];
    }
    int gid = blockIdx.x * 256 + t;
    Bsh[t >> 5][t & 31] = barS_next[gid];
    __syncthreads();
    int c = t & 31;
    const float* Brow = Bsh[t >> 5];
    float acc = 0.f;
#pragma unroll
    for (int d = 0; d < 32; d++) acc += Brow[d] * wmixT[d * 32 + c];
    barA[gid] = acc;
}

// ---------------- backward layer: barS_l and dEdr accumulation ----------------
__global__ __launch_bounds__(256) void k_bwd(
    const float* __restrict__ barS_next, const float* __restrict__ barA,
    const float* __restrict__ sl, const float* __restrict__ basis,
    const float* __restrict__ dbasis, const int* __restrict__ offs,
    const int* __restrict__ inc_k, const int* __restrict__ inc_nb,
    const float* __restrict__ Wrad_l, float* __restrict__ barS_out,
    float* __restrict__ dEdr)
{
    int t = threadIdx.x;
    int n = blockIdx.x * 8 + (t >> 5);
    int c = t & 31;
    float wr0[8];
#pragma unroll
    for (int bb = 0; bb < 8; bb++) wr0[bb] = Wrad_l[bb * 128 + c * 4];
    float myA = barA[n * 32 + c];
    float acc = barS_next[n * 32 + c];
    int j1 = offs[n + 1];
    for (int j = offs[n]; j < j1; j++) {
        int k = inc_k[j];
        int u = inc_nb[j] >> 1;
        const float4* bp = reinterpret_cast<const float4*>(basis  + (size_t)k * 8);
        const float4* dp = reinterpret_cast<const float4*>(dbasis + (size_t)k * 8);
        float4 b0 = bp[0], b1 = bp[1];
        float4 d0 = dp[0], d1 = dp[1];
        float R  = b0.x*wr0[0] + b0.y*wr0[1] + b0.z*wr0[2] + b0.w*wr0[3]
                 + b1.x*wr0[4] + b1.y*wr0[5] + b1.z*wr0[6] + b1.w*wr0[7];
        float dR = d0.x*wr0[0] + d0.y*wr0[1] + d0.z*wr0[2] + d0.w*wr0[3]
                 + d1.x*wr0[4] + d1.y*wr0[5] + d1.z*wr0[6] + d1.w*wr0[7];
        float su = sl[u * 32 + c];
        float bu = barA[u * 32 + c];
        acc += bu * R;                        // scatter-to-src, gather form
        float tc = dR * myA * su;             // contribution to dE/dr of edge k
#pragma unroll
        for (int o = 16; o; o >>= 1) tc += __shfl_xor(tc, o, 32);
        if (c == 0) atomicAdd(&dEdr[k], tc);
    }
    barS_out[n * 32 + c] = acc;
}

// ---------------- forces: F[n] = sum_inc (+/-) dEdr[k] * unit[k] ----------------
__global__ __launch_bounds__(256) void k_force(
    const int* __restrict__ offs, const int* __restrict__ inc_k, const int* __restrict__ inc_nb,
    const float* __restrict__ dEdr, const float* __restrict__ unit, float* __restrict__ out)
{
    int t = threadIdx.x;
    int n = blockIdx.x * 8 + (t >> 5);
    int lane = t & 31;
    float fx = 0.f, fy = 0.f, fz = 0.f;
    int j0 = offs[n], j1 = offs[n + 1];
    for (int j = j0 + lane; j < j1; j += 32) {
        int k  = inc_k[j];
        int nb = inc_nb[j];
        float sgn = (nb & 1) ? -1.f : 1.f;    // n==b -> -dEdr*unit ; n==a -> +dEdr*unit
        float g = sgn * dEdr[k];
        fx += g * unit[3*k+0];
        fy += g * unit[3*k+1];
        fz += g * unit[3*k+2];
    }
#pragma unroll
    for (int o = 16; o; o >>= 1) {
        fx += __shfl_xor(fx, o, 32);
        fy += __shfl_xor(fy, o, 32);
        fz += __shfl_xor(fz, o, 32);
    }
    if (lane == 0) {
        out[8 + n*3 + 0] = fx;
        out[8 + n*3 + 1] = fy;
        out[8 + n*3 + 2] = fz;
    }
}

// ---------------- per-frame energy ----------------
__global__ __launch_bounds__(256) void k_energy(
    const float* __restrict__ s3, const float* __restrict__ w_out, float* __restrict__ out)
{
    __shared__ float sm[256];
    int f = blockIdx.x, t = threadIdx.x;
    float acc = 0.f;
    for (int nn = t; nn < N_AT; nn += 256) {
        int n = f * N_AT + nn;
        float e = 0.f;
#pragma unroll
        for (int d = 0; d < 32; d++) e += s3[n * 32 + d] * w_out[d];
        acc += e;
    }
    sm[t] = acc;
    __syncthreads();
    for (int s = 128; s > 0; s >>= 1) {
        if (t < s) sm[t] += sm[t + s];
        __syncthreads();
    }
    if (t == 0) out[f] = sm[0];
}

extern "C" void kernel_launch(void* const* d_in, const int* in_sizes, int n_in,
                              void* d_out, int out_size, void* d_ws, size_t ws_size,
                              hipStream_t stream)
{
    const float* pos     = (const float*)d_in[0];
    const int*   eidx    = (const int*)  d_in[1];
    const float* cell    = (const float*)d_in[2];
    const int*   at      = (const int*)  d_in[3];
    const float* W_embed = (const float*)d_in[4];
    const float* W_rad   = (const float*)d_in[5];
    const float* W_mix   = (const float*)d_in[6];
    const float* w_out   = (const float*)d_in[7];
    const int*   co      = (const int*)  d_in[8];

    char* p = (char*)d_ws;
    auto carve = [&](size_t bytes) -> char* {
        char* r = p;
        p += (bytes + 255) & ~(size_t)255;
        return r;
    };
    float* basis  = (float*)carve((size_t)FE * 8 * 4);
    float* dbasis = (float*)carve((size_t)FE * 8 * 4);
    float* unit   = (float*)carve((size_t)FE * 3 * 4);
    float* s0     = (float*)carve((size_t)FN * 32 * 4);
    float* s1     = (float*)carve((size_t)FN * 32 * 4);
    float* s2     = (float*)carve((size_t)FN * 32 * 4);
    float* s3     = (float*)carve((size_t)FN * 32 * 4);
    float* barSa  = (float*)carve((size_t)FN * 32 * 4);
    float* barSb  = (float*)carve((size_t)FN * 32 * 4);
    float* barA   = (float*)carve((size_t)FN * 32 * 4);
    float* dEdr   = (float*)carve((size_t)FE * 4);
    int*   deg    = (int*)  carve((size_t)(FN + 1) * 4);
    int*   offs   = (int*)  carve((size_t)(FN + 1) * 4);
    int*   cur    = (int*)  carve((size_t)FN * 4);
    int*   inc_k  = (int*)  carve((size_t)2 * FE * 4);
    int*   inc_nb = (int*)  carve((size_t)2 * FE * 4);

    hipMemsetAsync(deg,  0, (size_t)(FN + 1) * 4, stream);
    hipMemsetAsync(cur,  0, (size_t)FN * 4,       stream);
    hipMemsetAsync(dEdr, 0, (size_t)FE * 4,       stream);

    k_edges<<<FE / 256, 256, 0, stream>>>(pos, eidx, cell, co, basis, dbasis, unit, deg);
    k_scan<<<1, 1024, 0, stream>>>(deg, offs);
    k_scatter<<<FE / 256, 256, 0, stream>>>(eidx, offs, cur, inc_k, inc_nb);
    k_embed<<<FN * 32 / 256, 256, 0, stream>>>(at, W_embed, s0);

    float* sArr[4] = { s0, s1, s2, s3 };
    for (int l = 0; l < 3; l++) {
        k_layer<<<FN / 8, 256, 0, stream>>>(sArr[l], sArr[l + 1], basis, offs, inc_k, inc_nb,
                                            W_rad + (size_t)l * 8 * 128, W_mix + (size_t)l * 1024);
    }

    k_initbars<<<FN * 32 / 256, 256, 0, stream>>>(w_out, barSa);
    float* bcur = barSa;
    float* bnext = barSb;
    for (int l = 2; l >= 0; l--) {
        k_barA<<<FN * 32 / 256, 256, 0, stream>>>(bcur, W_mix + (size_t)l * 1024, barA);
        k_bwd<<<FN / 8, 256, 0, stream>>>(bcur, barA, sArr[l], basis, dbasis, offs, inc_k, inc_nb,
                                          W_rad + (size_t)l * 8 * 128, bnext, dEdr);
        float* tmp = bcur; bcur = bnext; bnext = tmp;
    }

    k_force<<<FN / 8, 256, 0, stream>>>(offs, inc_k, inc_nb, dEdr, unit, (float*)d_out);
    k_energy<<<F_NUM, 256, 0, stream>>>(s3, w_out, (float*)d_out);
}

// Round 2
// 386.328 us; speedup vs baseline: 1.1706x; 1.1706x over previous
//
#include <hip/hip_runtime.h>
#include <math.h>

#define F_NUM 8
#define N_AT 2048
#define E_EDGE 32768
#define FE (F_NUM*E_EDGE)   // 262144 base edges
#define FN (F_NUM*N_AT)     // 16384 atoms
#define PI_F 3.14159265358979f

__device__ __forceinline__ float dot8(float4 a, float4 b, const float* w) {
    return a.x*w[0] + a.y*w[1] + a.z*w[2] + a.w*w[3]
         + b.x*w[4] + b.y*w[5] + b.z*w[6] + b.w*w[7];
}

// ---------------- edge geometry: basis, dbasis/dr, unit vectors, degree histogram ----------------
__global__ __launch_bounds__(256) void k_edges(
    const float* __restrict__ pos, const int* __restrict__ eidx,
    const float* __restrict__ cell, const int* __restrict__ co_p,
    float* __restrict__ basis, float* __restrict__ dbasis,
    float4* __restrict__ unit, int* __restrict__ deg)
{
    int k = blockIdx.x * 256 + threadIdx.x;
    if (k >= FE) return;
    int f = k >> 15;            // E = 32768
    int e = k & (E_EDGE - 1);
    int a = eidx[f * 2 * E_EDGE + e] + f * N_AT;
    int b = eidx[f * 2 * E_EDGE + E_EDGE + e] + f * N_AT;
    float co = (float)co_p[0];

    float vec[3];
#pragma unroll
    for (int d = 0; d < 3; d++) {
        float v  = pos[3 * b + d] - pos[3 * a + d];
        float cl = cell[3 * f + d];
        float sh = cl * ((v < -co ? 1.f : 0.f) - (v > co ? 1.f : 0.f));
        vec[d] = v + sh;
    }
    float r2   = vec[0]*vec[0] + vec[1]*vec[1] + vec[2]*vec[2] + 1e-12f;
    float r    = sqrtf(r2);
    float rinv = 1.f / r;
    unit[k] = make_float4(vec[0]*rinv, vec[1]*rinv, vec[2]*rinv, 0.f);

    float x = r * (1.f / 6.f);           // R_MAX = 6
    float env = 0.f, denv = 0.f;
    if (x < 1.f) {
        float x2 = x*x, x3 = x2*x, x5 = x2*x3, x6 = x5*x, x7 = x6*x, x8 = x7*x;
        env  = 1.f - 28.f*x6 + 48.f*x7 - 21.f*x8;
        denv = -168.f*x5 + 336.f*x6 - 168.f*x7;   // d env / d x
    }
    float s1, c1;
    sincosf(PI_F * x, &s1, &c1);
    float sn = s1, cn = c1;
    const float C0 = 0.57735026919f;     // sqrt(2/6)
    float bs[8], db[8];
#pragma unroll
    for (int n = 1; n <= 8; n++) {
        float kn  = (float)n * PI_F * (1.f / 6.f);
        float bes = C0 * sn * rinv;
        bs[n-1] = bes * env;
        db[n-1] = C0 * rinv * (kn * cn - sn * rinv) * env + bes * denv * (1.f / 6.f);
        float sn2 = sn * c1 + cn * s1;
        float cn2 = cn * c1 - sn * s1;
        sn = sn2; cn = cn2;
    }
    float4* bp = reinterpret_cast<float4*>(basis  + (size_t)k * 8);
    float4* dp = reinterpret_cast<float4*>(dbasis + (size_t)k * 8);
    bp[0] = make_float4(bs[0], bs[1], bs[2], bs[3]);
    bp[1] = make_float4(bs[4], bs[5], bs[6], bs[7]);
    dp[0] = make_float4(db[0], db[1], db[2], db[3]);
    dp[1] = make_float4(db[4], db[5], db[6], db[7]);

    atomicAdd(&deg[a], 1);
    atomicAdd(&deg[b], 1);
}

// ---------------- exclusive scan of degrees (FN = 16384 = 1024 threads x 16) ----------------
__global__ __launch_bounds__(1024) void k_scan(const int* __restrict__ deg, int* __restrict__ offs)
{
    __shared__ int sm[1024];
    int t = threadIdx.x;
    int base = t * 16;
    int loc[16];
    int s = 0;
#pragma unroll
    for (int i = 0; i < 16; i++) { loc[i] = s; s += deg[base + i]; }
    sm[t] = s;
    __syncthreads();
    for (int d = 1; d < 1024; d <<= 1) {
        int v = (t >= d) ? sm[t - d] : 0;
        __syncthreads();
        sm[t] += v;
        __syncthreads();
    }
    int pre = (t == 0) ? 0 : sm[t - 1];
#pragma unroll
    for (int i = 0; i < 16; i++) offs[base + i] = pre + loc[i];
    if (t == 1023) offs[FN] = sm[1023];
}

// ---------------- scatter incidences into CSR (packed int2: .x=edge, .y=(nbr<<1)|dirbit) ----------------
__global__ __launch_bounds__(256) void k_scatter(
    const int* __restrict__ eidx, const int* __restrict__ offs, int* __restrict__ cur,
    int2* __restrict__ inc)
{
    int k = blockIdx.x * 256 + threadIdx.x;
    if (k >= FE) return;
    int f = k >> 15;
    int e = k & (E_EDGE - 1);
    int a = eidx[f * 2 * E_EDGE + e] + f * N_AT;
    int b = eidx[f * 2 * E_EDGE + E_EDGE + e] + f * N_AT;
    int pa = atomicAdd(&cur[a], 1);
    inc[offs[a] + pa] = make_int2(k, (b << 1));        // n==a: dir bit 0 (+unit)
    int pb = atomicAdd(&cur[b], 1);
    inc[offs[b] + pb] = make_int2(k, (a << 1) | 1);    // n==b: dir bit 1 (-unit)
}

// ---------------- embedding ----------------
__global__ __launch_bounds__(256) void k_embed(
    const int* __restrict__ at, const float* __restrict__ W_embed, float* __restrict__ s0)
{
    int gid = blockIdx.x * 256 + threadIdx.x;   // FN*32
    int n = gid >> 5, c = gid & 31;
    s0[gid] = W_embed[at[n] * 32 + c];
}

// ---------------- forward layer: wave per atom, 2 j-streams x 32 channels, 2-way unroll ----------------
__global__ __launch_bounds__(256) void k_layer(
    const float* __restrict__ sl, float* __restrict__ slp1,
    const float* __restrict__ basis, const int* __restrict__ offs,
    const int2* __restrict__ inc,
    const float* __restrict__ Wrad_l, const float* __restrict__ Wmix_l)
{
    __shared__ float wmix[1024];
    __shared__ float Ash[4][32];
    int t = threadIdx.x;
    for (int i = t; i < 1024; i += 256) wmix[i] = Wmix_l[i];
    int w = t >> 6, lane = t & 63, c = lane & 31, h = lane >> 5;
    int n = blockIdx.x * 4 + w;
    float wr[8];
#pragma unroll
    for (int bb = 0; bb < 8; bb++) wr[bb] = Wrad_l[bb * 128 + c * 4];

    int jend = offs[n + 1];
    int j = offs[n] + h;                 // this half's stream, stride 2
    float A = 0.f;
    for (; j + 2 < jend; j += 4) {       // two stream elements per iter
        int2 i0 = inc[j], i1 = inc[j + 2];
        const float4* p0 = reinterpret_cast<const float4*>(basis + (size_t)i0.x * 8);
        const float4* p1 = reinterpret_cast<const float4*>(basis + (size_t)i1.x * 8);
        float4 a0 = p0[0], a1 = p0[1];
        float4 b0 = p1[0], b1 = p1[1];
        float sv0 = sl[(i0.y >> 1) * 32 + c];
        float sv1 = sl[(i1.y >> 1) * 32 + c];
        A += dot8(a0, a1, wr) * sv0 + dot8(b0, b1, wr) * sv1;
    }
    if (j < jend) {
        int2 i0 = inc[j];
        const float4* p0 = reinterpret_cast<const float4*>(basis + (size_t)i0.x * 8);
        A += dot8(p0[0], p0[1], wr) * sl[(i0.y >> 1) * 32 + c];
    }
    A += __shfl_xor(A, 32);
    if (h == 0) Ash[w][c] = A;
    __syncthreads();
    // s' = s + A @ Wmix   (split the cc-sum across the two halves)
    float acc = 0.f;
#pragma unroll
    for (int cc2 = 0; cc2 < 16; cc2++) {
        int cc = h * 16 + cc2;
        acc += Ash[w][cc] * wmix[cc * 32 + c];
    }
    acc += __shfl_xor(acc, 32);
    if (h == 0) slp1[n * 32 + c] = sl[n * 32 + c] + acc;
}

// ---------------- init barS3 = w_out (uniform over atoms) ----------------
__global__ __launch_bounds__(256) void k_initbars(const float* __restrict__ w_out, float* __restrict__ barS)
{
    int gid = blockIdx.x * 256 + threadIdx.x;
    barS[gid] = w_out[gid & 31];
}

// ---------------- barA[n,c] = sum_d barS_next[n,d] * Wmix[c,d] ----------------
__global__ __launch_bounds__(256) void k_barA(
    const float* __restrict__ barS_next, const float* __restrict__ Wmix_l, float* __restrict__ barA)
{
    __shared__ float wmixT[1024];   // [d][c]
    __shared__ float Bsh[8][32];
    int t = threadIdx.x;
    for (int i = t; i < 1024; i += 256) {
        int cc = i >> 5, dd = i & 31;
        wmixT[dd * 32 + cc] = Wmix_l[i];
    }
    int gid = blockIdx.x * 256 + t;
    Bsh[t >> 5][t & 31] = barS_next[gid];
    __syncthreads();
    int c = t & 31;
    const float* Brow = Bsh[t >> 5];
    float acc = 0.f;
#pragma unroll
    for (int d = 0; d < 32; d++) acc += Brow[d] * wmixT[d * 32 + c];
    barA[gid] = acc;
}

// ---------------- backward layer: barS_l = barS_{l+1} + sum_inc R * barA[u]  (pure gather) ----------------
__global__ __launch_bounds__(256) void k_bwd(
    const float* __restrict__ barS_next, const float* __restrict__ barA,
    const float* __restrict__ basis, const int* __restrict__ offs,
    const int2* __restrict__ inc,
    const float* __restrict__ Wrad_l, float* __restrict__ barS_out)
{
    int t = threadIdx.x;
    int w = t >> 6, lane = t & 63, c = lane & 31, h = lane >> 5;
    int n = blockIdx.x * 4 + w;
    float wr[8];
#pragma unroll
    for (int bb = 0; bb < 8; bb++) wr[bb] = Wrad_l[bb * 128 + c * 4];

    int jend = offs[n + 1];
    int j = offs[n] + h;
    float A = 0.f;
    for (; j + 2 < jend; j += 4) {
        int2 i0 = inc[j], i1 = inc[j + 2];
        const float4* p0 = reinterpret_cast<const float4*>(basis + (size_t)i0.x * 8);
        const float4* p1 = reinterpret_cast<const float4*>(basis + (size_t)i1.x * 8);
        float4 a0 = p0[0], a1 = p0[1];
        float4 b0 = p1[0], b1 = p1[1];
        float bv0 = barA[(i0.y >> 1) * 32 + c];
        float bv1 = barA[(i1.y >> 1) * 32 + c];
        A += dot8(a0, a1, wr) * bv0 + dot8(b0, b1, wr) * bv1;
    }
    if (j < jend) {
        int2 i0 = inc[j];
        const float4* p0 = reinterpret_cast<const float4*>(basis + (size_t)i0.x * 8);
        A += dot8(p0[0], p0[1], wr) * barA[(i0.y >> 1) * 32 + c];
    }
    A += __shfl_xor(A, 32);
    if (h == 0) barS_out[n * 32 + c] = barS_next[n * 32 + c] + A;
}

// ---------------- forces: per-lane partial over all incidences & layers; one reduction per atom ----------------
__global__ __launch_bounds__(256) void k_force(
    const float* __restrict__ s0, const float* __restrict__ s1, const float* __restrict__ s2,
    const float* __restrict__ ba0, const float* __restrict__ ba1, const float* __restrict__ ba2,
    const float* __restrict__ dbasis, const float4* __restrict__ unit,
    const int* __restrict__ offs, const int2* __restrict__ inc,
    const float* __restrict__ W_rad, float* __restrict__ out)
{
    int t = threadIdx.x;
    int w = t >> 6, lane = t & 63, c = lane & 31, h = lane >> 5;
    int n = blockIdx.x * 4 + w;
    float wr[3][8];
#pragma unroll
    for (int l = 0; l < 3; l++)
#pragma unroll
        for (int bb = 0; bb < 8; bb++) wr[l][bb] = W_rad[l * 1024 + bb * 128 + c * 4];

    float mys[3] = { s0[n * 32 + c], s1[n * 32 + c], s2[n * 32 + c] };
    float myb[3] = { ba0[n * 32 + c], ba1[n * 32 + c], ba2[n * 32 + c] };

    float Fx = 0.f, Fy = 0.f, Fz = 0.f;
    int jend = offs[n + 1];
    int j = offs[n] + h;
    for (; j < jend; j += 2) {
        int2 i0 = inc[j];
        int k = i0.x, u = i0.y >> 1;
        const float4* dp = reinterpret_cast<const float4*>(dbasis + (size_t)k * 8);
        float4 d0 = dp[0], d1 = dp[1];
        float4 uv = unit[k];
        float su0 = s0[u * 32 + c], su1 = s1[u * 32 + c], su2 = s2[u * 32 + c];
        float bu0 = ba0[u * 32 + c], bu1 = ba1[u * 32 + c], bu2 = ba2[u * 32 + c];
        float tc = dot8(d0, d1, wr[0]) * (myb[0] * su0 + bu0 * mys[0])
                 + dot8(d0, d1, wr[1]) * (myb[1] * su1 + bu1 * mys[1])
                 + dot8(d0, d1, wr[2]) * (myb[2] * su2 + bu2 * mys[2]);
        tc = (i0.y & 1) ? -tc : tc;
        Fx += tc * uv.x; Fy += tc * uv.y; Fz += tc * uv.z;
    }
#pragma unroll
    for (int o = 1; o <= 32; o <<= 1) {
        Fx += __shfl_xor(Fx, o);
        Fy += __shfl_xor(Fy, o);
        Fz += __shfl_xor(Fz, o);
    }
    if (lane == 0) {
        out[8 + n * 3 + 0] = Fx;
        out[8 + n * 3 + 1] = Fy;
        out[8 + n * 3 + 2] = Fz;
    }
}

// ---------------- per-frame energy ----------------
__global__ __launch_bounds__(256) void k_energy(
    const float* __restrict__ s3, const float* __restrict__ w_out, float* __restrict__ out)
{
    __shared__ float sm[256];
    int f = blockIdx.x, t = threadIdx.x;
    float acc = 0.f;
    for (int nn = t; nn < N_AT; nn += 256) {
        int n = f * N_AT + nn;
        float e = 0.f;
#pragma unroll
        for (int d = 0; d < 32; d++) e += s3[n * 32 + d] * w_out[d];
        acc += e;
    }
    sm[t] = acc;
    __syncthreads();
    for (int s = 128; s > 0; s >>= 1) {
        if (t < s) sm[t] += sm[t + s];
        __syncthreads();
    }
    if (t == 0) out[f] = sm[0];
}

extern "C" void kernel_launch(void* const* d_in, const int* in_sizes, int n_in,
                              void* d_out, int out_size, void* d_ws, size_t ws_size,
                              hipStream_t stream)
{
    const float* pos     = (const float*)d_in[0];
    const int*   eidx    = (const int*)  d_in[1];
    const float* cell    = (const float*)d_in[2];
    const int*   at      = (const int*)  d_in[3];
    const float* W_embed = (const float*)d_in[4];
    const float* W_rad   = (const float*)d_in[5];
    const float* W_mix   = (const float*)d_in[6];
    const float* w_out   = (const float*)d_in[7];
    const int*   co      = (const int*)  d_in[8];

    char* p = (char*)d_ws;
    auto carve = [&](size_t bytes) -> char* {
        char* r = p;
        p += (bytes + 255) & ~(size_t)255;
        return r;
    };
    float*  basis  = (float*) carve((size_t)FE * 8 * 4);
    float*  dbasis = (float*) carve((size_t)FE * 8 * 4);
    float4* unit   = (float4*)carve((size_t)FE * 16);
    float*  s0     = (float*) carve((size_t)FN * 32 * 4);
    float*  s1     = (float*) carve((size_t)FN * 32 * 4);
    float*  s2     = (float*) carve((size_t)FN * 32 * 4);
    float*  s3     = (float*) carve((size_t)FN * 32 * 4);
    float*  barSa  = (float*) carve((size_t)FN * 32 * 4);
    float*  barSb  = (float*) carve((size_t)FN * 32 * 4);
    float*  barA0  = (float*) carve((size_t)FN * 32 * 4);
    float*  barA1  = (float*) carve((size_t)FN * 32 * 4);
    float*  barA2  = (float*) carve((size_t)FN * 32 * 4);
    int*    deg    = (int*)   carve((size_t)(FN + 1) * 4);
    int*    offs   = (int*)   carve((size_t)(FN + 1) * 4);
    int*    cur    = (int*)   carve((size_t)FN * 4);
    int2*   inc    = (int2*)  carve((size_t)2 * FE * 8);

    hipMemsetAsync(deg, 0, (size_t)(FN + 1) * 4, stream);
    hipMemsetAsync(cur, 0, (size_t)FN * 4,       stream);

    k_edges<<<FE / 256, 256, 0, stream>>>(pos, eidx, cell, co, basis, dbasis, unit, deg);
    k_scan<<<1, 1024, 0, stream>>>(deg, offs);
    k_scatter<<<FE / 256, 256, 0, stream>>>(eidx, offs, cur, inc);
    k_embed<<<FN * 32 / 256, 256, 0, stream>>>(at, W_embed, s0);

    float* sArr[4] = { s0, s1, s2, s3 };
    for (int l = 0; l < 3; l++) {
        k_layer<<<FN / 4, 256, 0, stream>>>(sArr[l], sArr[l + 1], basis, offs, inc,
                                            W_rad + (size_t)l * 8 * 128, W_mix + (size_t)l * 1024);
    }

    k_initbars<<<FN * 32 / 256, 256, 0, stream>>>(w_out, barSa);
    // l=2: barA2 from barS3(=barSa); barS2 -> barSb
    k_barA<<<FN * 32 / 256, 256, 0, stream>>>(barSa, W_mix + 2 * 1024, barA2);
    k_bwd<<<FN / 4, 256, 0, stream>>>(barSa, barA2, basis, offs, inc,
                                      W_rad + (size_t)2 * 8 * 128, barSb);
    // l=1: barA1 from barS2(=barSb); barS1 -> barSa
    k_barA<<<FN * 32 / 256, 256, 0, stream>>>(barSb, W_mix + 1 * 1024, barA1);
    k_bwd<<<FN / 4, 256, 0, stream>>>(barSb, barA1, basis, offs, inc,
                                      W_rad + (size_t)1 * 8 * 128, barSa);
    // l=0: only barA0 needed (s0 has no position dependence)
    k_barA<<<FN * 32 / 256, 256, 0, stream>>>(barSa, W_mix + 0 * 1024, barA0);

    k_force<<<FN / 4, 256, 0, stream>>>(s0, s1, s2, barA0, barA1, barA2,
                                        dbasis, unit, offs, inc, W_rad, (float*)d_out);
    k_energy<<<F_NUM, 256, 0, stream>>>(s3, w_out, (float*)d_out);
}

// Round 3
// 316.807 us; speedup vs baseline: 1.4275x; 1.2194x over previous
//
#include <hip/hip_runtime.h>
#include <math.h>

#define F_NUM 8
#define N_AT 2048
#define E_EDGE 32768
#define FE (F_NUM*E_EDGE)   // 262144 base edges
#define FN (F_NUM*N_AT)     // 16384 atoms
#define PI_F 3.14159265358979f

__device__ __forceinline__ unsigned short f2b(float x) {
    unsigned int u = __float_as_uint(x);
    u += 0x8000u;
    return (unsigned short)(u >> 16);
}
__device__ __forceinline__ float blo(unsigned int u) { return __uint_as_float(u << 16); }
__device__ __forceinline__ float bhi(unsigned int u) { return __uint_as_float(u & 0xffff0000u); }

// dot of 8 bf16-packed values (uint4) with 8 f32 weights
__device__ __forceinline__ float dot8q(uint4 q, const float* w) {
    return blo(q.x)*w[0] + bhi(q.x)*w[1] + blo(q.y)*w[2] + bhi(q.y)*w[3]
         + blo(q.z)*w[4] + bhi(q.z)*w[5] + blo(q.w)*w[6] + bhi(q.w)*w[7];
}

// ---------------- edge geometry: bf16-packed basis/dbasis, unit vectors, degree histogram ----------------
__global__ __launch_bounds__(256) void k_edges(
    const float* __restrict__ pos, const int* __restrict__ eidx,
    const float* __restrict__ cell, const int* __restrict__ co_p,
    uint4* __restrict__ basisq, uint4* __restrict__ dbasisq,
    float4* __restrict__ unit, int* __restrict__ deg)
{
    int k = blockIdx.x * 256 + threadIdx.x;
    if (k >= FE) return;
    int f = k >> 15;
    int e = k & (E_EDGE - 1);
    int a = eidx[f * 2 * E_EDGE + e] + f * N_AT;
    int b = eidx[f * 2 * E_EDGE + E_EDGE + e] + f * N_AT;
    float co = (float)co_p[0];

    float vec[3];
#pragma unroll
    for (int d = 0; d < 3; d++) {
        float v  = pos[3 * b + d] - pos[3 * a + d];
        float cl = cell[3 * f + d];
        float sh = cl * ((v < -co ? 1.f : 0.f) - (v > co ? 1.f : 0.f));
        vec[d] = v + sh;
    }
    float r2   = vec[0]*vec[0] + vec[1]*vec[1] + vec[2]*vec[2] + 1e-12f;
    float r    = sqrtf(r2);
    float rinv = 1.f / r;
    unit[k] = make_float4(vec[0]*rinv, vec[1]*rinv, vec[2]*rinv, 0.f);

    float x = r * (1.f / 6.f);           // R_MAX = 6
    float env = 0.f, denv = 0.f;
    if (x < 1.f) {
        float x2 = x*x, x3 = x2*x, x5 = x2*x3, x6 = x5*x, x7 = x6*x, x8 = x7*x;
        env  = 1.f - 28.f*x6 + 48.f*x7 - 21.f*x8;
        denv = -168.f*x5 + 336.f*x6 - 168.f*x7;
    }
    float s1, c1;
    sincosf(PI_F * x, &s1, &c1);
    float sn = s1, cn = c1;
    const float C0 = 0.57735026919f;     // sqrt(2/6)
    float bs[8], db[8];
#pragma unroll
    for (int n = 1; n <= 8; n++) {
        float kn  = (float)n * PI_F * (1.f / 6.f);
        float bes = C0 * sn * rinv;
        bs[n-1] = bes * env;
        db[n-1] = C0 * rinv * (kn * cn - sn * rinv) * env + bes * denv * (1.f / 6.f);
        float sn2 = sn * c1 + cn * s1;
        float cn2 = cn * c1 - sn * s1;
        sn = sn2; cn = cn2;
    }
    uint4 B, D;
    B.x = (unsigned)f2b(bs[0]) | ((unsigned)f2b(bs[1]) << 16);
    B.y = (unsigned)f2b(bs[2]) | ((unsigned)f2b(bs[3]) << 16);
    B.z = (unsigned)f2b(bs[4]) | ((unsigned)f2b(bs[5]) << 16);
    B.w = (unsigned)f2b(bs[6]) | ((unsigned)f2b(bs[7]) << 16);
    D.x = (unsigned)f2b(db[0]) | ((unsigned)f2b(db[1]) << 16);
    D.y = (unsigned)f2b(db[2]) | ((unsigned)f2b(db[3]) << 16);
    D.z = (unsigned)f2b(db[4]) | ((unsigned)f2b(db[5]) << 16);
    D.w = (unsigned)f2b(db[6]) | ((unsigned)f2b(db[7]) << 16);
    basisq[k] = B;
    dbasisq[k] = D;

    atomicAdd(&deg[a], 1);
    atomicAdd(&deg[b], 1);
}

// ---------------- exclusive scan of degrees ----------------
__global__ __launch_bounds__(1024) void k_scan(const int* __restrict__ deg, int* __restrict__ offs)
{
    __shared__ int sm[1024];
    int t = threadIdx.x;
    int base = t * 16;
    int loc[16];
    int s = 0;
#pragma unroll
    for (int i = 0; i < 16; i++) { loc[i] = s; s += deg[base + i]; }
    sm[t] = s;
    __syncthreads();
    for (int d = 1; d < 1024; d <<= 1) {
        int v = (t >= d) ? sm[t - d] : 0;
        __syncthreads();
        sm[t] += v;
        __syncthreads();
    }
    int pre = (t == 0) ? 0 : sm[t - 1];
#pragma unroll
    for (int i = 0; i < 16; i++) offs[base + i] = pre + loc[i];
    if (t == 1023) offs[FN] = sm[1023];
}

// ---------------- scatter incidences into CSR ----------------
__global__ __launch_bounds__(256) void k_scatter(
    const int* __restrict__ eidx, const int* __restrict__ offs, int* __restrict__ cur,
    int2* __restrict__ inc)
{
    int k = blockIdx.x * 256 + threadIdx.x;
    if (k >= FE) return;
    int f = k >> 15;
    int e = k & (E_EDGE - 1);
    int a = eidx[f * 2 * E_EDGE + e] + f * N_AT;
    int b = eidx[f * 2 * E_EDGE + E_EDGE + e] + f * N_AT;
    int pa = atomicAdd(&cur[a], 1);
    inc[offs[a] + pa] = make_int2(k, (b << 1));
    int pb = atomicAdd(&cur[b], 1);
    inc[offs[b] + pb] = make_int2(k, (a << 1) | 1);
}

// ---------------- g2[c] = sum_d w_out[d] * Wmix2[c,d]  (barA for layer 2 is atom-uniform) ----------------
__global__ void k_g2(const float* __restrict__ w_out, const float* __restrict__ Wmix2, float* __restrict__ g2)
{
    int c = threadIdx.x;
    float acc = 0.f;
#pragma unroll
    for (int d = 0; d < 32; d++) acc += w_out[d] * Wmix2[c * 32 + d];
    g2[c] = acc;
}

// ---------------- forward layer (L0: gather from 4-row embed table in LDS) ----------------
template<bool L0>
__global__ __launch_bounds__(256) void k_layer_t(
    const float* __restrict__ sl, const int* __restrict__ at,
    const float* __restrict__ W_embed, float* __restrict__ slp1,
    const uint4* __restrict__ basisq, const int* __restrict__ offs,
    const int2* __restrict__ inc,
    const float* __restrict__ Wrad_l, const float* __restrict__ Wmix_l)
{
    __shared__ float wmix[1024];
    __shared__ float Ash[4][32];
    __shared__ float We[128];
    int t = threadIdx.x;
    for (int i = t; i < 1024; i += 256) wmix[i] = Wmix_l[i];
    if (L0 && t < 128) We[t] = W_embed[t];
    int w = t >> 6, lane = t & 63, c = lane & 31, h = lane >> 5;
    int n = blockIdx.x * 4 + w;
    float wr[8];
#pragma unroll
    for (int bb = 0; bb < 8; bb++) wr[bb] = Wrad_l[bb * 128 + c * 4];
    __syncthreads();

    int jend = offs[n + 1];
    int j = offs[n] + h;
    float A = 0.f;
    for (; j + 6 < jend; j += 8) {
        int2 e0 = inc[j], e1 = inc[j + 2], e2 = inc[j + 4], e3 = inc[j + 6];
        uint4 b0 = basisq[e0.x], b1 = basisq[e1.x], b2 = basisq[e2.x], b3 = basisq[e3.x];
        float sv0, sv1, sv2, sv3;
        if (L0) {
            sv0 = We[at[e0.y >> 1] * 32 + c];
            sv1 = We[at[e1.y >> 1] * 32 + c];
            sv2 = We[at[e2.y >> 1] * 32 + c];
            sv3 = We[at[e3.y >> 1] * 32 + c];
        } else {
            sv0 = sl[(e0.y >> 1) * 32 + c];
            sv1 = sl[(e1.y >> 1) * 32 + c];
            sv2 = sl[(e2.y >> 1) * 32 + c];
            sv3 = sl[(e3.y >> 1) * 32 + c];
        }
        A += dot8q(b0, wr) * sv0 + dot8q(b1, wr) * sv1
           + dot8q(b2, wr) * sv2 + dot8q(b3, wr) * sv3;
    }
    for (; j < jend; j += 2) {
        int2 e0 = inc[j];
        uint4 b0 = basisq[e0.x];
        float sv0 = L0 ? We[at[e0.y >> 1] * 32 + c] : sl[(e0.y >> 1) * 32 + c];
        A += dot8q(b0, wr) * sv0;
    }
    A += __shfl_xor(A, 32);
    if (h == 0) Ash[w][c] = A;
    __syncthreads();
    float base = L0 ? We[at[n] * 32 + c] : sl[n * 32 + c];
    float acc = 0.f;
#pragma unroll
    for (int cc2 = 0; cc2 < 16; cc2++) {
        int cc = h * 16 + cc2;
        acc += Ash[w][cc] * wmix[cc * 32 + c];
    }
    acc += __shfl_xor(acc, 32);
    if (h == 0) slp1[n * 32 + c] = base + acc;
}

// ---------------- barA[n,c] = sum_d barS_next[n,d] * Wmix[c,d] ----------------
__global__ __launch_bounds__(256) void k_barA(
    const float* __restrict__ barS_next, const float* __restrict__ Wmix_l, float* __restrict__ barA)
{
    __shared__ float wmixT[1024];   // [d][c]
    __shared__ float Bsh[8][32];
    int t = threadIdx.x;
    for (int i = t; i < 1024; i += 256) {
        int cc = i >> 5, dd = i & 31;
        wmixT[dd * 32 + cc] = Wmix_l[i];
    }
    int gid = blockIdx.x * 256 + t;
    Bsh[t >> 5][t & 31] = barS_next[gid];
    __syncthreads();
    int c = t & 31;
    const float* Brow = Bsh[t >> 5];
    float acc = 0.f;
#pragma unroll
    for (int d = 0; d < 32; d++) acc += Brow[d] * wmixT[d * 32 + c];
    barA[gid] = acc;
}

// ---------------- backward layer 2: barS2 = w_out + g2 * sum_inc R2  (no per-lane gather) ----------------
__global__ __launch_bounds__(256) void k_bwd2(
    const float* __restrict__ w_out, const float* __restrict__ g2,
    const uint4* __restrict__ basisq, const int* __restrict__ offs,
    const int2* __restrict__ inc,
    const float* __restrict__ Wrad_l, float* __restrict__ barS_out)
{
    int t = threadIdx.x;
    int w = t >> 6, lane = t & 63, c = lane & 31, h = lane >> 5;
    int n = blockIdx.x * 4 + w;
    float wr[8];
#pragma unroll
    for (int bb = 0; bb < 8; bb++) wr[bb] = Wrad_l[bb * 128 + c * 4];
    int jend = offs[n + 1];
    int j = offs[n] + h;
    float S = 0.f;
    for (; j + 6 < jend; j += 8) {
        int2 e0 = inc[j], e1 = inc[j + 2], e2 = inc[j + 4], e3 = inc[j + 6];
        uint4 b0 = basisq[e0.x], b1 = basisq[e1.x], b2 = basisq[e2.x], b3 = basisq[e3.x];
        S += dot8q(b0, wr) + dot8q(b1, wr) + dot8q(b2, wr) + dot8q(b3, wr);
    }
    for (; j < jend; j += 2) {
        int2 e0 = inc[j];
        S += dot8q(basisq[e0.x], wr);
    }
    S += __shfl_xor(S, 32);
    if (h == 0) barS_out[n * 32 + c] = w_out[c] + g2[c] * S;
}

// ---------------- backward layer (general): barS_l = barS_{l+1} + sum_inc R * barA[u] ----------------
__global__ __launch_bounds__(256) void k_bwd(
    const float* __restrict__ barS_next, const float* __restrict__ barA,
    const uint4* __restrict__ basisq, const int* __restrict__ offs,
    const int2* __restrict__ inc,
    const float* __restrict__ Wrad_l, float* __restrict__ barS_out)
{
    int t = threadIdx.x;
    int w = t >> 6, lane = t & 63, c = lane & 31, h = lane >> 5;
    int n = blockIdx.x * 4 + w;
    float wr[8];
#pragma unroll
    for (int bb = 0; bb < 8; bb++) wr[bb] = Wrad_l[bb * 128 + c * 4];
    int jend = offs[n + 1];
    int j = offs[n] + h;
    float A = 0.f;
    for (; j + 6 < jend; j += 8) {
        int2 e0 = inc[j], e1 = inc[j + 2], e2 = inc[j + 4], e3 = inc[j + 6];
        uint4 b0 = basisq[e0.x], b1 = basisq[e1.x], b2 = basisq[e2.x], b3 = basisq[e3.x];
        float v0 = barA[(e0.y >> 1) * 32 + c];
        float v1 = barA[(e1.y >> 1) * 32 + c];
        float v2 = barA[(e2.y >> 1) * 32 + c];
        float v3 = barA[(e3.y >> 1) * 32 + c];
        A += dot8q(b0, wr) * v0 + dot8q(b1, wr) * v1
           + dot8q(b2, wr) * v2 + dot8q(b3, wr) * v3;
    }
    for (; j < jend; j += 2) {
        int2 e0 = inc[j];
        A += dot8q(basisq[e0.x], wr) * barA[(e0.y >> 1) * 32 + c];
    }
    A += __shfl_xor(A, 32);
    if (h == 0) barS_out[n * 32 + c] = barS_next[n * 32 + c] + A;
}

// ---------------- pack per-(atom,channel) force operands into 8x bf16 (one uint4) ----------------
// q.x: lo=s0, hi=s1 ; q.y: lo=s2, hi=ba0 ; q.z: lo=ba1
__global__ __launch_bounds__(256) void k_pack(
    const int* __restrict__ at, const float* __restrict__ W_embed,
    const float* __restrict__ s1, const float* __restrict__ s2,
    const float* __restrict__ ba0, const float* __restrict__ ba1,
    uint4* __restrict__ pk)
{
    int gid = blockIdx.x * 256 + threadIdx.x;   // FN*32
    int n = gid >> 5, c = gid & 31;
    float s0v = W_embed[at[n] * 32 + c];
    uint4 v;
    v.x = (unsigned)f2b(s0v)      | ((unsigned)f2b(s1[gid])  << 16);
    v.y = (unsigned)f2b(s2[gid])  | ((unsigned)f2b(ba0[gid]) << 16);
    v.z = (unsigned)f2b(ba1[gid]);
    v.w = 0;
    pk[gid] = v;
}

// ---------------- forces: single packed gather per neighbor, 2-way unroll ----------------
__global__ __launch_bounds__(256) void k_force(
    const uint4* __restrict__ pk, const float* __restrict__ g2,
    const uint4* __restrict__ dbq, const float4* __restrict__ unit,
    const int* __restrict__ offs, const int2* __restrict__ inc,
    const float* __restrict__ W_rad, float* __restrict__ out)
{
    int t = threadIdx.x;
    int w = t >> 6, lane = t & 63, c = lane & 31, h = lane >> 5;
    int n = blockIdx.x * 4 + w;
    float wr0[8], wr1[8], wr2[8];
#pragma unroll
    for (int bb = 0; bb < 8; bb++) {
        wr0[bb] = W_rad[0 * 1024 + bb * 128 + c * 4];
        wr1[bb] = W_rad[1 * 1024 + bb * 128 + c * 4];
        wr2[bb] = W_rad[2 * 1024 + bb * 128 + c * 4];
    }
    uint4 mq = pk[n * 32 + c];
    float ms0 = blo(mq.x), ms1 = bhi(mq.x), ms2 = blo(mq.y);
    float mb0 = bhi(mq.y), mb1 = blo(mq.z);
    float g2c = g2[c];
    float Fx = 0.f, Fy = 0.f, Fz = 0.f;
    int jend = offs[n + 1];
    int j = offs[n] + h;
    for (; j + 2 < jend; j += 4) {
        int2 e0 = inc[j], e1 = inc[j + 2];
        uint4 q0 = pk[(e0.y >> 1) * 32 + c];
        uint4 q1 = pk[(e1.y >> 1) * 32 + c];
        uint4 d0 = dbq[e0.x], d1 = dbq[e1.x];
        float4 u0 = unit[e0.x], u1 = unit[e1.x];
        float tc0 = dot8q(d0, wr0) * (mb0 * blo(q0.x) + bhi(q0.y) * ms0)
                  + dot8q(d0, wr1) * (mb1 * bhi(q0.x) + blo(q0.z) * ms1)
                  + dot8q(d0, wr2) * g2c * (blo(q0.y) + ms2);
        tc0 = (e0.y & 1) ? -tc0 : tc0;
        Fx += tc0 * u0.x; Fy += tc0 * u0.y; Fz += tc0 * u0.z;
        float tc1 = dot8q(d1, wr0) * (mb0 * blo(q1.x) + bhi(q1.y) * ms0)
                  + dot8q(d1, wr1) * (mb1 * bhi(q1.x) + blo(q1.z) * ms1)
                  + dot8q(d1, wr2) * g2c * (blo(q1.y) + ms2);
        tc1 = (e1.y & 1) ? -tc1 : tc1;
        Fx += tc1 * u1.x; Fy += tc1 * u1.y; Fz += tc1 * u1.z;
    }
    if (j < jend) {
        int2 e0 = inc[j];
        uint4 q0 = pk[(e0.y >> 1) * 32 + c];
        uint4 d0 = dbq[e0.x];
        float4 u0 = unit[e0.x];
        float tc0 = dot8q(d0, wr0) * (mb0 * blo(q0.x) + bhi(q0.y) * ms0)
                  + dot8q(d0, wr1) * (mb1 * bhi(q0.x) + blo(q0.z) * ms1)
                  + dot8q(d0, wr2) * g2c * (blo(q0.y) + ms2);
        tc0 = (e0.y & 1) ? -tc0 : tc0;
        Fx += tc0 * u0.x; Fy += tc0 * u0.y; Fz += tc0 * u0.z;
    }
#pragma unroll
    for (int o = 1; o <= 32; o <<= 1) {
        Fx += __shfl_xor(Fx, o);
        Fy += __shfl_xor(Fy, o);
        Fz += __shfl_xor(Fz, o);
    }
    if (lane == 0) {
        out[8 + n * 3 + 0] = Fx;
        out[8 + n * 3 + 1] = Fy;
        out[8 + n * 3 + 2] = Fz;
    }
}

// ---------------- per-frame energy ----------------
__global__ __launch_bounds__(256) void k_energy(
    const float* __restrict__ s3, const float* __restrict__ w_out, float* __restrict__ out)
{
    __shared__ float sm[256];
    int f = blockIdx.x, t = threadIdx.x;
    float acc = 0.f;
    for (int nn = t; nn < N_AT; nn += 256) {
        int n = f * N_AT + nn;
        float e = 0.f;
#pragma unroll
        for (int d = 0; d < 32; d++) e += s3[n * 32 + d] * w_out[d];
        acc += e;
    }
    sm[t] = acc;
    __syncthreads();
    for (int s = 128; s > 0; s >>= 1) {
        if (t < s) sm[t] += sm[t + s];
        __syncthreads();
    }
    if (t == 0) out[f] = sm[0];
}

extern "C" void kernel_launch(void* const* d_in, const int* in_sizes, int n_in,
                              void* d_out, int out_size, void* d_ws, size_t ws_size,
                              hipStream_t stream)
{
    const float* pos     = (const float*)d_in[0];
    const int*   eidx    = (const int*)  d_in[1];
    const float* cell    = (const float*)d_in[2];
    const int*   at      = (const int*)  d_in[3];
    const float* W_embed = (const float*)d_in[4];
    const float* W_rad   = (const float*)d_in[5];
    const float* W_mix   = (const float*)d_in[6];
    const float* w_out   = (const float*)d_in[7];
    const int*   co      = (const int*)  d_in[8];

    char* p = (char*)d_ws;
    auto carve = [&](size_t bytes) -> char* {
        char* r = p;
        p += (bytes + 255) & ~(size_t)255;
        return r;
    };
    uint4*  basisq = (uint4*) carve((size_t)FE * 16);
    uint4*  dbq    = (uint4*) carve((size_t)FE * 16);
    float4* unit   = (float4*)carve((size_t)FE * 16);
    float*  s1     = (float*) carve((size_t)FN * 32 * 4);
    float*  s2     = (float*) carve((size_t)FN * 32 * 4);
    float*  s3     = (float*) carve((size_t)FN * 32 * 4);
    float*  barSa  = (float*) carve((size_t)FN * 32 * 4);
    float*  barSb  = (float*) carve((size_t)FN * 32 * 4);
    float*  barA0  = (float*) carve((size_t)FN * 32 * 4);
    float*  barA1  = (float*) carve((size_t)FN * 32 * 4);
    uint4*  pk     = (uint4*) carve((size_t)FN * 32 * 16);
    float*  g2     = (float*) carve(32 * 4);
    int*    deg    = (int*)   carve((size_t)(FN + 1) * 4);
    int*    offs   = (int*)   carve((size_t)(FN + 1) * 4);
    int*    cur    = (int*)   carve((size_t)FN * 4);
    int2*   inc    = (int2*)  carve((size_t)2 * FE * 8);

    hipMemsetAsync(deg, 0, (size_t)(FN + 1) * 4, stream);
    hipMemsetAsync(cur, 0, (size_t)FN * 4,       stream);

    k_edges<<<FE / 256, 256, 0, stream>>>(pos, eidx, cell, co, basisq, dbq, unit, deg);
    k_scan<<<1, 1024, 0, stream>>>(deg, offs);
    k_scatter<<<FE / 256, 256, 0, stream>>>(eidx, offs, cur, inc);
    k_g2<<<1, 32, 0, stream>>>(w_out, W_mix + 2 * 1024, g2);

    // forward
    k_layer_t<true><<<FN / 4, 256, 0, stream>>>(nullptr, at, W_embed, s1, basisq, offs, inc,
                                                W_rad + 0 * 1024, W_mix + 0 * 1024);
    k_layer_t<false><<<FN / 4, 256, 0, stream>>>(s1, at, W_embed, s2, basisq, offs, inc,
                                                 W_rad + 1 * 1024, W_mix + 1 * 1024);
    k_layer_t<false><<<FN / 4, 256, 0, stream>>>(s2, at, W_embed, s3, basisq, offs, inc,
                                                 W_rad + 2 * 1024, W_mix + 2 * 1024);
    k_energy<<<F_NUM, 256, 0, stream>>>(s3, w_out, (float*)d_out);

    // backward
    k_bwd2<<<FN / 4, 256, 0, stream>>>(w_out, g2, basisq, offs, inc, W_rad + 2 * 1024, barSb);
    k_barA<<<FN * 32 / 256, 256, 0, stream>>>(barSb, W_mix + 1 * 1024, barA1);
    k_bwd<<<FN / 4, 256, 0, stream>>>(barSb, barA1, basisq, offs, inc, W_rad + 1 * 1024, barSa);
    k_barA<<<FN * 32 / 256, 256, 0, stream>>>(barSa, W_mix + 0 * 1024, barA0);

    // forces
    k_pack<<<FN * 32 / 256, 256, 0, stream>>>(at, W_embed, s1, s2, barA0, barA1, pk);
    k_force<<<FN / 4, 256, 0, stream>>>(pk, g2, dbq, unit, offs, inc, W_rad, (float*)d_out);
}

// Round 4
// 308.658 us; speedup vs baseline: 1.4652x; 1.0264x over previous
//
#include <hip/hip_runtime.h>
#include <math.h>

#define F_NUM 8
#define N_AT 2048
#define E_EDGE 32768
#define FE (F_NUM*E_EDGE)   // 262144 base edges
#define FN (F_NUM*N_AT)     // 16384 atoms
#define CAP 72              // per-atom incidence capacity (avg 32, Poisson; P(overflow) ~ 1e-12)
#define PI_F 3.14159265358979f

__device__ __forceinline__ unsigned short f2b(float x) {
    unsigned int u = __float_as_uint(x);
    u += 0x8000u;
    return (unsigned short)(u >> 16);
}
__device__ __forceinline__ float blo(unsigned int u) { return __uint_as_float(u << 16); }
__device__ __forceinline__ float bhi(unsigned int u) { return __uint_as_float(u & 0xffff0000u); }

// dot of 8 bf16-packed values (uint4) with 8 f32 weights
__device__ __forceinline__ float dot8q(uint4 q, const float* w) {
    return blo(q.x)*w[0] + bhi(q.x)*w[1] + blo(q.y)*w[2] + bhi(q.y)*w[3]
         + blo(q.z)*w[4] + bhi(q.z)*w[5] + blo(q.w)*w[6] + bhi(q.w)*w[7];
}

// ---------------- edges: geometry + bf16 basis/dbasis + unit + DIRECT scatter into padded lists ----------------
__global__ __launch_bounds__(256) void k_edges(
    const float* __restrict__ pos, const int* __restrict__ eidx,
    const float* __restrict__ cell, const int* __restrict__ co_p,
    uint4* __restrict__ basisq, uint4* __restrict__ dbasisq,
    float4* __restrict__ unit, int* __restrict__ cnt, int2* __restrict__ inc)
{
    int k = blockIdx.x * 256 + threadIdx.x;
    if (k >= FE) return;
    int f = k >> 15;
    int e = k & (E_EDGE - 1);
    int a = eidx[f * 2 * E_EDGE + e] + f * N_AT;
    int b = eidx[f * 2 * E_EDGE + E_EDGE + e] + f * N_AT;
    float co = (float)co_p[0];

    float vec[3];
#pragma unroll
    for (int d = 0; d < 3; d++) {
        float v  = pos[3 * b + d] - pos[3 * a + d];
        float cl = cell[3 * f + d];
        float sh = cl * ((v < -co ? 1.f : 0.f) - (v > co ? 1.f : 0.f));
        vec[d] = v + sh;
    }
    float r2   = vec[0]*vec[0] + vec[1]*vec[1] + vec[2]*vec[2] + 1e-12f;
    float r    = sqrtf(r2);
    float rinv = 1.f / r;
    unit[k] = make_float4(vec[0]*rinv, vec[1]*rinv, vec[2]*rinv, 0.f);

    float x = r * (1.f / 6.f);           // R_MAX = 6
    float env = 0.f, denv = 0.f;
    if (x < 1.f) {
        float x2 = x*x, x3 = x2*x, x5 = x2*x3, x6 = x5*x, x7 = x6*x, x8 = x7*x;
        env  = 1.f - 28.f*x6 + 48.f*x7 - 21.f*x8;
        denv = -168.f*x5 + 336.f*x6 - 168.f*x7;
    }
    float s1, c1;
    sincosf(PI_F * x, &s1, &c1);
    float sn = s1, cn = c1;
    const float C0 = 0.57735026919f;     // sqrt(2/6)
    float bs[8], db[8];
#pragma unroll
    for (int n = 1; n <= 8; n++) {
        float kn  = (float)n * PI_F * (1.f / 6.f);
        float bes = C0 * sn * rinv;
        bs[n-1] = bes * env;
        db[n-1] = C0 * rinv * (kn * cn - sn * rinv) * env + bes * denv * (1.f / 6.f);
        float sn2 = sn * c1 + cn * s1;
        float cn2 = cn * c1 - sn * s1;
        sn = sn2; cn = cn2;
    }
    uint4 B, D;
    B.x = (unsigned)f2b(bs[0]) | ((unsigned)f2b(bs[1]) << 16);
    B.y = (unsigned)f2b(bs[2]) | ((unsigned)f2b(bs[3]) << 16);
    B.z = (unsigned)f2b(bs[4]) | ((unsigned)f2b(bs[5]) << 16);
    B.w = (unsigned)f2b(bs[6]) | ((unsigned)f2b(bs[7]) << 16);
    D.x = (unsigned)f2b(db[0]) | ((unsigned)f2b(db[1]) << 16);
    D.y = (unsigned)f2b(db[2]) | ((unsigned)f2b(db[3]) << 16);
    D.z = (unsigned)f2b(db[4]) | ((unsigned)f2b(db[5]) << 16);
    D.w = (unsigned)f2b(db[6]) | ((unsigned)f2b(db[7]) << 16);
    basisq[k] = B;
    dbasisq[k] = D;

    int sa = atomicAdd(&cnt[a], 1);
    if (sa < CAP) inc[a * CAP + sa] = make_int2(k, (b << 1));        // n==a: +unit
    int sb = atomicAdd(&cnt[b], 1);
    if (sb < CAP) inc[b * CAP + sb] = make_int2(k, (a << 1) | 1);    // n==b: -unit
}

// ---------------- g2[c] = sum_d w_out[d] * Wmix2[c,d] ----------------
__global__ void k_g2(const float* __restrict__ w_out, const float* __restrict__ Wmix2, float* __restrict__ g2)
{
    int c = threadIdx.x;
    float acc = 0.f;
#pragma unroll
    for (int d = 0; d < 32; d++) acc += w_out[d] * Wmix2[c * 32 + d];
    g2[c] = acc;
}

// ---------------- forward layer (L0: embed table in LDS) ----------------
template<bool L0>
__global__ __launch_bounds__(256) void k_L(
    const float* __restrict__ sl, const int* __restrict__ at,
    const float* __restrict__ W_embed, float* __restrict__ slp1,
    const uint4* __restrict__ basisq, const int* __restrict__ cnt,
    const int2* __restrict__ inc,
    const float* __restrict__ Wrad_l, const float* __restrict__ Wmix_l)
{
    __shared__ float wmix[1024];
    __shared__ float Ash[4][32];
    __shared__ float We[128];
    int t = threadIdx.x;
    for (int i = t; i < 1024; i += 256) wmix[i] = Wmix_l[i];
    if (L0 && t < 128) We[t] = W_embed[t];
    int w = t >> 6, lane = t & 63, c = lane & 31, h = lane >> 5;
    int n = blockIdx.x * 4 + w;
    float wr[8];
#pragma unroll
    for (int bb = 0; bb < 8; bb++) wr[bb] = Wrad_l[bb * 128 + c * 4];
    __syncthreads();

    int cn = min(cnt[n], CAP);
    int h1 = (cn + 1) >> 1;
    int base = n * CAP;
    int j    = base + (h ? h1 : 0);
    int jend = base + (h ? cn : h1);
    float A = 0.f;
    for (; j + 3 < jend; j += 4) {
        int2 e0 = inc[j], e1 = inc[j+1], e2 = inc[j+2], e3 = inc[j+3];
        uint4 b0 = basisq[e0.x], b1 = basisq[e1.x], b2 = basisq[e2.x], b3 = basisq[e3.x];
        float sv0, sv1, sv2, sv3;
        if (L0) {
            sv0 = We[at[e0.y >> 1] * 32 + c];
            sv1 = We[at[e1.y >> 1] * 32 + c];
            sv2 = We[at[e2.y >> 1] * 32 + c];
            sv3 = We[at[e3.y >> 1] * 32 + c];
        } else {
            sv0 = sl[(e0.y >> 1) * 32 + c];
            sv1 = sl[(e1.y >> 1) * 32 + c];
            sv2 = sl[(e2.y >> 1) * 32 + c];
            sv3 = sl[(e3.y >> 1) * 32 + c];
        }
        A += dot8q(b0, wr) * sv0 + dot8q(b1, wr) * sv1
           + dot8q(b2, wr) * sv2 + dot8q(b3, wr) * sv3;
    }
    for (; j < jend; ++j) {
        int2 e0 = inc[j];
        uint4 b0 = basisq[e0.x];
        float sv0 = L0 ? We[at[e0.y >> 1] * 32 + c] : sl[(e0.y >> 1) * 32 + c];
        A += dot8q(b0, wr) * sv0;
    }
    A += __shfl_xor(A, 32);
    if (h == 0) Ash[w][c] = A;
    __syncthreads();
    float base_s = L0 ? We[at[n] * 32 + c] : sl[n * 32 + c];
    float acc = 0.f;
#pragma unroll
    for (int cc2 = 0; cc2 < 16; cc2++) {
        int cc = h * 16 + cc2;
        acc += Ash[w][cc] * wmix[cc * 32 + c];
    }
    acc += __shfl_xor(acc, 32);
    if (h == 0) slp1[n * 32 + c] = base_s + acc;
}

// ---------------- layer 2 fused: energy + barS2 + barA1 (no s3) ----------------
__global__ __launch_bounds__(256) void k_L2E(
    const float* __restrict__ s2, const uint4* __restrict__ basisq,
    const int* __restrict__ cnt, const int2* __restrict__ inc,
    const float* __restrict__ Wrad2, const float* __restrict__ Wmix1,
    const float* __restrict__ w_out, const float* __restrict__ g2,
    float* __restrict__ barS2, float* __restrict__ barA1, float* __restrict__ out)
{
    __shared__ float wmixT[1024];   // Wmix1 transposed: [d][c]
    __shared__ float Bsh[4][32];
    __shared__ float ev[4];
    int t = threadIdx.x;
    for (int i = t; i < 1024; i += 256) wmixT[(i & 31) * 32 + (i >> 5)] = Wmix1[i];
    int w = t >> 6, lane = t & 63, c = lane & 31, h = lane >> 5;
    int n = blockIdx.x * 4 + w;
    float wr[8];
#pragma unroll
    for (int bb = 0; bb < 8; bb++) wr[bb] = Wrad2[bb * 128 + c * 4];

    int cn = min(cnt[n], CAP);
    int h1 = (cn + 1) >> 1;
    int base = n * CAP;
    int j    = base + (h ? h1 : 0);
    int jend = base + (h ? cn : h1);
    float A = 0.f, S = 0.f;
    for (; j + 3 < jend; j += 4) {
        int2 e0 = inc[j], e1 = inc[j+1], e2 = inc[j+2], e3 = inc[j+3];
        uint4 b0 = basisq[e0.x], b1 = basisq[e1.x], b2 = basisq[e2.x], b3 = basisq[e3.x];
        float r0 = dot8q(b0, wr), r1 = dot8q(b1, wr), r2 = dot8q(b2, wr), r3 = dot8q(b3, wr);
        A += r0 * s2[(e0.y >> 1) * 32 + c] + r1 * s2[(e1.y >> 1) * 32 + c]
           + r2 * s2[(e2.y >> 1) * 32 + c] + r3 * s2[(e3.y >> 1) * 32 + c];
        S += r0 + r1 + r2 + r3;
    }
    for (; j < jend; ++j) {
        int2 e0 = inc[j];
        float r0 = dot8q(basisq[e0.x], wr);
        A += r0 * s2[(e0.y >> 1) * 32 + c];
        S += r0;
    }
    A += __shfl_xor(A, 32);
    S += __shfl_xor(S, 32);

    float woc = w_out[c], g2c = g2[c];
    float s2n = s2[n * 32 + c];
    // energy: e_n = sum_c s2[n,c]*w_out[c] + A2[c]*g2[c]
    float te = s2n * woc + A * g2c;
#pragma unroll
    for (int o = 1; o <= 16; o <<= 1) te += __shfl_xor(te, o);
    if (lane == 0) ev[w] = te;
    float bs2 = woc + g2c * S;
    if (h == 0) { barS2[n * 32 + c] = bs2; Bsh[w][c] = bs2; }
    __syncthreads();
    float acc = 0.f;
#pragma unroll
    for (int dd2 = 0; dd2 < 16; dd2++) {
        int d = h * 16 + dd2;
        acc += Bsh[w][d] * wmixT[d * 32 + c];
    }
    acc += __shfl_xor(acc, 32);
    if (h == 0) barA1[n * 32 + c] = acc;
    if (t == 0) atomicAdd(&out[(blockIdx.x * 4) >> 11], ev[0] + ev[1] + ev[2] + ev[3]);
}

// ---------------- backward l=1 fused: barS1 -> barA0 -> pk (packed force operands) ----------------
__global__ __launch_bounds__(256) void k_B1F(
    const float* __restrict__ barA1, const float* __restrict__ barS2,
    const float* __restrict__ s1, const float* __restrict__ s2,
    const uint4* __restrict__ basisq, const int* __restrict__ cnt,
    const int2* __restrict__ inc,
    const float* __restrict__ Wrad1, const float* __restrict__ Wmix0,
    float* __restrict__ barA0, uint2* __restrict__ pk)
{
    __shared__ float wmixT[1024];   // Wmix0 transposed: [d][c]
    __shared__ float Bsh[4][32];
    int t = threadIdx.x;
    for (int i = t; i < 1024; i += 256) wmixT[(i & 31) * 32 + (i >> 5)] = Wmix0[i];
    int w = t >> 6, lane = t & 63, c = lane & 31, h = lane >> 5;
    int n = blockIdx.x * 4 + w;
    float wr[8];
#pragma unroll
    for (int bb = 0; bb < 8; bb++) wr[bb] = Wrad1[bb * 128 + c * 4];

    int cn = min(cnt[n], CAP);
    int h1 = (cn + 1) >> 1;
    int base = n * CAP;
    int j    = base + (h ? h1 : 0);
    int jend = base + (h ? cn : h1);
    float A = 0.f;
    for (; j + 3 < jend; j += 4) {
        int2 e0 = inc[j], e1 = inc[j+1], e2 = inc[j+2], e3 = inc[j+3];
        uint4 b0 = basisq[e0.x], b1 = basisq[e1.x], b2 = basisq[e2.x], b3 = basisq[e3.x];
        A += dot8q(b0, wr) * barA1[(e0.y >> 1) * 32 + c]
           + dot8q(b1, wr) * barA1[(e1.y >> 1) * 32 + c]
           + dot8q(b2, wr) * barA1[(e2.y >> 1) * 32 + c]
           + dot8q(b3, wr) * barA1[(e3.y >> 1) * 32 + c];
    }
    for (; j < jend; ++j) {
        int2 e0 = inc[j];
        A += dot8q(basisq[e0.x], wr) * barA1[(e0.y >> 1) * 32 + c];
    }
    A += __shfl_xor(A, 32);
    float bs1 = barS2[n * 32 + c] + A;
    if (h == 0) Bsh[w][c] = bs1;
    __syncthreads();
    float acc = 0.f;
#pragma unroll
    for (int dd2 = 0; dd2 < 16; dd2++) {
        int d = h * 16 + dd2;
        acc += Bsh[w][d] * wmixT[d * 32 + c];
    }
    acc += __shfl_xor(acc, 32);     // barA0[n,c]
    if (h == 0) {
        barA0[n * 32 + c] = acc;
        uint2 v;
        v.x = (unsigned)f2b(s1[n * 32 + c]) | ((unsigned)f2b(s2[n * 32 + c]) << 16);
        v.y = (unsigned)f2b(acc)            | ((unsigned)f2b(barA1[n * 32 + c]) << 16);
        pk[n * 32 + c] = v;
    }
}

// ---------------- forces: 4-way unrolled gather; s0 via embed LDS table ----------------
__global__ __launch_bounds__(256) void k_force(
    const uint2* __restrict__ pk, const int* __restrict__ at,
    const float* __restrict__ W_embed, const float* __restrict__ g2,
    const float* __restrict__ barA0, const float* __restrict__ barA1,
    const float* __restrict__ s1, const float* __restrict__ s2,
    const uint4* __restrict__ dbq, const float4* __restrict__ unit,
    const int* __restrict__ cnt, const int2* __restrict__ inc,
    const float* __restrict__ W_rad, float* __restrict__ out)
{
    __shared__ float We[128];
    int t = threadIdx.x;
    if (t < 128) We[t] = W_embed[t];
    int w = t >> 6, lane = t & 63, c = lane & 31, h = lane >> 5;
    int n = blockIdx.x * 4 + w;
    float wr0[8], wr1[8], wr2[8];
#pragma unroll
    for (int bb = 0; bb < 8; bb++) {
        wr0[bb] = W_rad[0 * 1024 + bb * 128 + c * 4];
        wr1[bb] = W_rad[1 * 1024 + bb * 128 + c * 4];
        wr2[bb] = W_rad[2 * 1024 + bb * 128 + c * 4];
    }
    __syncthreads();
    float ms0 = We[at[n] * 32 + c];
    float ms1 = s1[n * 32 + c], ms2 = s2[n * 32 + c];
    float mb0 = barA0[n * 32 + c], mb1 = barA1[n * 32 + c];
    float g2c = g2[c];

    float Fx = 0.f, Fy = 0.f, Fz = 0.f;
    int cn = min(cnt[n], CAP);
    int h1 = (cn + 1) >> 1;
    int base = n * CAP;
    int j    = base + (h ? h1 : 0);
    int jend = base + (h ? cn : h1);

    for (; j + 3 < jend; j += 4) {
        int2 e0 = inc[j], e1 = inc[j+1], e2 = inc[j+2], e3 = inc[j+3];
        int u0 = e0.y >> 1, u1 = e1.y >> 1, u2 = e2.y >> 1, u3 = e3.y >> 1;
        uint2 q0 = pk[u0 * 32 + c], q1 = pk[u1 * 32 + c], q2 = pk[u2 * 32 + c], q3 = pk[u3 * 32 + c];
        uint4 d0 = dbq[e0.x], d1 = dbq[e1.x], d2 = dbq[e2.x], d3 = dbq[e3.x];
        float4 v0 = unit[e0.x], v1 = unit[e1.x], v2 = unit[e2.x], v3 = unit[e3.x];
        float a0 = We[at[u0] * 32 + c], a1 = We[at[u1] * 32 + c];
        float a2 = We[at[u2] * 32 + c], a3 = We[at[u3] * 32 + c];
        float tc0 = dot8q(d0, wr0) * (mb0 * a0 + blo(q0.y) * ms0)
                  + dot8q(d0, wr1) * (mb1 * blo(q0.x) + bhi(q0.y) * ms1)
                  + dot8q(d0, wr2) * g2c * (bhi(q0.x) + ms2);
        tc0 = (e0.y & 1) ? -tc0 : tc0;
        Fx += tc0 * v0.x; Fy += tc0 * v0.y; Fz += tc0 * v0.z;
        float tc1 = dot8q(d1, wr0) * (mb0 * a1 + blo(q1.y) * ms0)
                  + dot8q(d1, wr1) * (mb1 * blo(q1.x) + bhi(q1.y) * ms1)
                  + dot8q(d1, wr2) * g2c * (bhi(q1.x) + ms2);
        tc1 = (e1.y & 1) ? -tc1 : tc1;
        Fx += tc1 * v1.x; Fy += tc1 * v1.y; Fz += tc1 * v1.z;
        float tc2 = dot8q(d2, wr0) * (mb0 * a2 + blo(q2.y) * ms0)
                  + dot8q(d2, wr1) * (mb1 * blo(q2.x) + bhi(q2.y) * ms1)
                  + dot8q(d2, wr2) * g2c * (bhi(q2.x) + ms2);
        tc2 = (e2.y & 1) ? -tc2 : tc2;
        Fx += tc2 * v2.x; Fy += tc2 * v2.y; Fz += tc2 * v2.z;
        float tc3 = dot8q(d3, wr0) * (mb0 * a3 + blo(q3.y) * ms0)
                  + dot8q(d3, wr1) * (mb1 * blo(q3.x) + bhi(q3.y) * ms1)
                  + dot8q(d3, wr2) * g2c * (bhi(q3.x) + ms2);
        tc3 = (e3.y & 1) ? -tc3 : tc3;
        Fx += tc3 * v3.x; Fy += tc3 * v3.y; Fz += tc3 * v3.z;
    }
    for (; j < jend; ++j) {
        int2 e0 = inc[j];
        int u0 = e0.y >> 1;
        uint2 q0 = pk[u0 * 32 + c];
        uint4 d0 = dbq[e0.x];
        float4 v0 = unit[e0.x];
        float a0 = We[at[u0] * 32 + c];
        float tc0 = dot8q(d0, wr0) * (mb0 * a0 + blo(q0.y) * ms0)
                  + dot8q(d0, wr1) * (mb1 * blo(q0.x) + bhi(q0.y) * ms1)
                  + dot8q(d0, wr2) * g2c * (bhi(q0.x) + ms2);
        tc0 = (e0.y & 1) ? -tc0 : tc0;
        Fx += tc0 * v0.x; Fy += tc0 * v0.y; Fz += tc0 * v0.z;
    }
#pragma unroll
    for (int o = 1; o <= 32; o <<= 1) {
        Fx += __shfl_xor(Fx, o);
        Fy += __shfl_xor(Fy, o);
        Fz += __shfl_xor(Fz, o);
    }
    if (lane == 0) {
        out[8 + n * 3 + 0] = Fx;
        out[8 + n * 3 + 1] = Fy;
        out[8 + n * 3 + 2] = Fz;
    }
}

extern "C" void kernel_launch(void* const* d_in, const int* in_sizes, int n_in,
                              void* d_out, int out_size, void* d_ws, size_t ws_size,
                              hipStream_t stream)
{
    const float* pos     = (const float*)d_in[0];
    const int*   eidx    = (const int*)  d_in[1];
    const float* cell    = (const float*)d_in[2];
    const int*   at      = (const int*)  d_in[3];
    const float* W_embed = (const float*)d_in[4];
    const float* W_rad   = (const float*)d_in[5];
    const float* W_mix   = (const float*)d_in[6];
    const float* w_out   = (const float*)d_in[7];
    const int*   co      = (const int*)  d_in[8];

    char* p = (char*)d_ws;
    auto carve = [&](size_t bytes) -> char* {
        char* r = p;
        p += (bytes + 255) & ~(size_t)255;
        return r;
    };
    uint4*  basisq = (uint4*) carve((size_t)FE * 16);
    uint4*  dbq    = (uint4*) carve((size_t)FE * 16);
    float4* unit   = (float4*)carve((size_t)FE * 16);
    float*  s1     = (float*) carve((size_t)FN * 32 * 4);
    float*  s2     = (float*) carve((size_t)FN * 32 * 4);
    float*  barS2  = (float*) carve((size_t)FN * 32 * 4);
    float*  barA1  = (float*) carve((size_t)FN * 32 * 4);
    float*  barA0  = (float*) carve((size_t)FN * 32 * 4);
    uint2*  pk     = (uint2*) carve((size_t)FN * 32 * 8);
    float*  g2     = (float*) carve(32 * 4);
    int*    cnt    = (int*)   carve((size_t)FN * 4);
    int2*   inc    = (int2*)  carve((size_t)FN * CAP * 8);

    hipMemsetAsync(cnt, 0, (size_t)FN * 4, stream);
    hipMemsetAsync(d_out, 0, F_NUM * 4, stream);   // energy accumulators

    k_edges<<<FE / 256, 256, 0, stream>>>(pos, eidx, cell, co, basisq, dbq, unit, cnt, inc);
    k_g2<<<1, 32, 0, stream>>>(w_out, W_mix + 2 * 1024, g2);

    // forward
    k_L<true><<<FN / 4, 256, 0, stream>>>(nullptr, at, W_embed, s1, basisq, cnt, inc,
                                          W_rad + 0 * 1024, W_mix + 0 * 1024);
    k_L<false><<<FN / 4, 256, 0, stream>>>(s1, at, W_embed, s2, basisq, cnt, inc,
                                           W_rad + 1 * 1024, W_mix + 1 * 1024);
    // layer 2 + energy + barS2 + barA1
    k_L2E<<<FN / 4, 256, 0, stream>>>(s2, basisq, cnt, inc, W_rad + 2 * 1024,
                                      W_mix + 1 * 1024, w_out, g2, barS2, barA1, (float*)d_out);
    // backward l=1 + barA0 + pack
    k_B1F<<<FN / 4, 256, 0, stream>>>(barA1, barS2, s1, s2, basisq, cnt, inc,
                                      W_rad + 1 * 1024, W_mix + 0 * 1024, barA0, pk);
    // forces
    k_force<<<FN / 4, 256, 0, stream>>>(pk, at, W_embed, g2, barA0, barA1, s1, s2,
                                        dbq, unit, cnt, inc, W_rad, (float*)d_out);
}

// Round 5
// 288.214 us; speedup vs baseline: 1.5691x; 1.0709x over previous
//
#include <hip/hip_runtime.h>
#include <math.h>

#define F_NUM 8
#define N_AT 2048
#define E_EDGE 32768
#define FE (F_NUM*E_EDGE)   // 262144 base edges
#define FN (F_NUM*N_AT)     // 16384 atoms
#define CAP 72              // per-atom incidence capacity (avg 32, Poisson)
#define PI_F 3.14159265358979f

__device__ __forceinline__ unsigned short f2b(float x) {
    unsigned int u = __float_as_uint(x);
    u += 0x8000u;
    return (unsigned short)(u >> 16);
}
__device__ __forceinline__ float blo(unsigned int u) { return __uint_as_float(u << 16); }
__device__ __forceinline__ float bhi(unsigned int u) { return __uint_as_float(u & 0xffff0000u); }
__device__ __forceinline__ float b2f(unsigned short u) { return __uint_as_float((unsigned)u << 16); }

// dot of 8 bf16-packed values (uint4) with 8 f32 weights
__device__ __forceinline__ float dot8q(uint4 q, const float* w) {
    return blo(q.x)*w[0] + bhi(q.x)*w[1] + blo(q.y)*w[2] + bhi(q.y)*w[3]
         + blo(q.z)*w[4] + bhi(q.z)*w[5] + blo(q.w)*w[6] + bhi(q.w)*w[7];
}

// ---------------- edges: geometry + bf16 basis/dbasis + unit + direct scatter into padded lists ----------------
__global__ __launch_bounds__(256) void k_edges(
    const float* __restrict__ pos, const int* __restrict__ eidx,
    const float* __restrict__ cell, const int* __restrict__ co_p,
    uint4* __restrict__ basisq, uint4* __restrict__ dbasisq,
    float4* __restrict__ unit, int* __restrict__ cnt, int2* __restrict__ inc)
{
    int k = blockIdx.x * 256 + threadIdx.x;
    if (k >= FE) return;
    int f = k >> 15;
    int e = k & (E_EDGE - 1);
    int a = eidx[f * 2 * E_EDGE + e] + f * N_AT;
    int b = eidx[f * 2 * E_EDGE + E_EDGE + e] + f * N_AT;
    float co = (float)co_p[0];

    float vec[3];
#pragma unroll
    for (int d = 0; d < 3; d++) {
        float v  = pos[3 * b + d] - pos[3 * a + d];
        float cl = cell[3 * f + d];
        float sh = cl * ((v < -co ? 1.f : 0.f) - (v > co ? 1.f : 0.f));
        vec[d] = v + sh;
    }
    float r2   = vec[0]*vec[0] + vec[1]*vec[1] + vec[2]*vec[2] + 1e-12f;
    float r    = sqrtf(r2);
    float rinv = 1.f / r;
    unit[k] = make_float4(vec[0]*rinv, vec[1]*rinv, vec[2]*rinv, 0.f);

    float x = r * (1.f / 6.f);           // R_MAX = 6
    float env = 0.f, denv = 0.f;
    if (x < 1.f) {
        float x2 = x*x, x3 = x2*x, x5 = x2*x3, x6 = x5*x, x7 = x6*x, x8 = x7*x;
        env  = 1.f - 28.f*x6 + 48.f*x7 - 21.f*x8;
        denv = -168.f*x5 + 336.f*x6 - 168.f*x7;
    }
    float s1, c1;
    sincosf(PI_F * x, &s1, &c1);
    float sn = s1, cn = c1;
    const float C0 = 0.57735026919f;     // sqrt(2/6)
    float bs[8], db[8];
#pragma unroll
    for (int n = 1; n <= 8; n++) {
        float kn  = (float)n * PI_F * (1.f / 6.f);
        float bes = C0 * sn * rinv;
        bs[n-1] = bes * env;
        db[n-1] = C0 * rinv * (kn * cn - sn * rinv) * env + bes * denv * (1.f / 6.f);
        float sn2 = sn * c1 + cn * s1;
        float cn2 = cn * c1 - sn * s1;
        sn = sn2; cn = cn2;
    }
    uint4 B, D;
    B.x = (unsigned)f2b(bs[0]) | ((unsigned)f2b(bs[1]) << 16);
    B.y = (unsigned)f2b(bs[2]) | ((unsigned)f2b(bs[3]) << 16);
    B.z = (unsigned)f2b(bs[4]) | ((unsigned)f2b(bs[5]) << 16);
    B.w = (unsigned)f2b(bs[6]) | ((unsigned)f2b(bs[7]) << 16);
    D.x = (unsigned)f2b(db[0]) | ((unsigned)f2b(db[1]) << 16);
    D.y = (unsigned)f2b(db[2]) | ((unsigned)f2b(db[3]) << 16);
    D.z = (unsigned)f2b(db[4]) | ((unsigned)f2b(db[5]) << 16);
    D.w = (unsigned)f2b(db[6]) | ((unsigned)f2b(db[7]) << 16);
    basisq[k] = B;
    dbasisq[k] = D;

    int sa = atomicAdd(&cnt[a], 1);
    if (sa < CAP) inc[a * CAP + sa] = make_int2(k, (b << 1));        // n==a: +unit
    int sb = atomicAdd(&cnt[b], 1);
    if (sb < CAP) inc[b * CAP + sb] = make_int2(k, (a << 1) | 1);    // n==b: -unit
}

// ---------------- g2[c] = sum_d w_out[d] * Wmix2[c,d] ----------------
__global__ void k_g2(const float* __restrict__ w_out, const float* __restrict__ Wmix2, float* __restrict__ g2)
{
    int c = threadIdx.x;
    float acc = 0.f;
#pragma unroll
    for (int d = 0; d < 32; d++) acc += w_out[d] * Wmix2[c * 32 + d];
    g2[c] = acc;
}

// ---------------- forward layer; features stored/gathered as bf16 rows ----------------
template<bool L0>
__global__ __launch_bounds__(256) void k_L(
    const unsigned short* __restrict__ slq, const int* __restrict__ at,
    const float* __restrict__ W_embed, unsigned short* __restrict__ soq,
    const uint4* __restrict__ basisq, const int* __restrict__ cnt,
    const int2* __restrict__ inc,
    const float* __restrict__ Wrad_l, const float* __restrict__ Wmix_l)
{
    __shared__ float wmix[1024];
    __shared__ float Ash[4][32];
    __shared__ float We[128];
    int t = threadIdx.x;
    for (int i = t; i < 1024; i += 256) wmix[i] = Wmix_l[i];
    if (L0 && t < 128) We[t] = W_embed[t];
    int w = t >> 6, lane = t & 63, c = lane & 31, h = lane >> 5;
    int n = blockIdx.x * 4 + w;
    float wr[8];
#pragma unroll
    for (int bb = 0; bb < 8; bb++) wr[bb] = Wrad_l[bb * 128 + c * 4];
    __syncthreads();

    int cn = min(cnt[n], CAP);
    int h1 = (cn + 1) >> 1;
    int base = n * CAP;
    int j    = base + (h ? h1 : 0);
    int jend = base + (h ? cn : h1);
    float A = 0.f;
    for (; j + 3 < jend; j += 4) {
        int2 e0 = inc[j], e1 = inc[j+1], e2 = inc[j+2], e3 = inc[j+3];
        uint4 b0 = basisq[e0.x], b1 = basisq[e1.x], b2 = basisq[e2.x], b3 = basisq[e3.x];
        float sv0, sv1, sv2, sv3;
        if (L0) {
            sv0 = We[at[e0.y >> 1] * 32 + c];
            sv1 = We[at[e1.y >> 1] * 32 + c];
            sv2 = We[at[e2.y >> 1] * 32 + c];
            sv3 = We[at[e3.y >> 1] * 32 + c];
        } else {
            sv0 = b2f(slq[(e0.y >> 1) * 32 + c]);
            sv1 = b2f(slq[(e1.y >> 1) * 32 + c]);
            sv2 = b2f(slq[(e2.y >> 1) * 32 + c]);
            sv3 = b2f(slq[(e3.y >> 1) * 32 + c]);
        }
        A += dot8q(b0, wr) * sv0 + dot8q(b1, wr) * sv1
           + dot8q(b2, wr) * sv2 + dot8q(b3, wr) * sv3;
    }
    for (; j < jend; ++j) {
        int2 e0 = inc[j];
        uint4 b0 = basisq[e0.x];
        float sv0 = L0 ? We[at[e0.y >> 1] * 32 + c] : b2f(slq[(e0.y >> 1) * 32 + c]);
        A += dot8q(b0, wr) * sv0;
    }
    A += __shfl_xor(A, 32);
    if (h == 0) Ash[w][c] = A;
    __syncthreads();
    float base_s = L0 ? We[at[n] * 32 + c] : b2f(slq[n * 32 + c]);
    float acc = 0.f;
#pragma unroll
    for (int cc2 = 0; cc2 < 16; cc2++) {
        int cc = h * 16 + cc2;
        acc += Ash[w][cc] * wmix[cc * 32 + c];
    }
    acc += __shfl_xor(acc, 32);
    if (h == 0) soq[n * 32 + c] = f2b(base_s + acc);
}

// ---------------- layer 2 fused: energy + barS2 + barA1(bf16) ----------------
__global__ __launch_bounds__(256) void k_L2E(
    const unsigned short* __restrict__ s2q, const uint4* __restrict__ basisq,
    const int* __restrict__ cnt, const int2* __restrict__ inc,
    const float* __restrict__ Wrad2, const float* __restrict__ Wmix1,
    const float* __restrict__ w_out, const float* __restrict__ g2,
    float* __restrict__ barS2, unsigned short* __restrict__ ba1q, float* __restrict__ out)
{
    __shared__ float wmixT[1024];   // Wmix1 transposed: [d][c]
    __shared__ float Bsh[4][32];
    __shared__ float ev[4];
    int t = threadIdx.x;
    for (int i = t; i < 1024; i += 256) wmixT[(i & 31) * 32 + (i >> 5)] = Wmix1[i];
    int w = t >> 6, lane = t & 63, c = lane & 31, h = lane >> 5;
    int n = blockIdx.x * 4 + w;
    float wr[8];
#pragma unroll
    for (int bb = 0; bb < 8; bb++) wr[bb] = Wrad2[bb * 128 + c * 4];

    int cn = min(cnt[n], CAP);
    int h1 = (cn + 1) >> 1;
    int base = n * CAP;
    int j    = base + (h ? h1 : 0);
    int jend = base + (h ? cn : h1);
    float A = 0.f, S = 0.f;
    for (; j + 3 < jend; j += 4) {
        int2 e0 = inc[j], e1 = inc[j+1], e2 = inc[j+2], e3 = inc[j+3];
        uint4 b0 = basisq[e0.x], b1 = basisq[e1.x], b2 = basisq[e2.x], b3 = basisq[e3.x];
        float r0 = dot8q(b0, wr), r1 = dot8q(b1, wr), r2 = dot8q(b2, wr), r3 = dot8q(b3, wr);
        A += r0 * b2f(s2q[(e0.y >> 1) * 32 + c]) + r1 * b2f(s2q[(e1.y >> 1) * 32 + c])
           + r2 * b2f(s2q[(e2.y >> 1) * 32 + c]) + r3 * b2f(s2q[(e3.y >> 1) * 32 + c]);
        S += r0 + r1 + r2 + r3;
    }
    for (; j < jend; ++j) {
        int2 e0 = inc[j];
        float r0 = dot8q(basisq[e0.x], wr);
        A += r0 * b2f(s2q[(e0.y >> 1) * 32 + c]);
        S += r0;
    }
    A += __shfl_xor(A, 32);
    S += __shfl_xor(S, 32);

    float woc = w_out[c], g2c = g2[c];
    float s2n = b2f(s2q[n * 32 + c]);
    float te = s2n * woc + A * g2c;     // energy contribution of atom n (per channel)
#pragma unroll
    for (int o = 1; o <= 16; o <<= 1) te += __shfl_xor(te, o);
    if (lane == 0) ev[w] = te;
    float bs2 = woc + g2c * S;
    if (h == 0) { barS2[n * 32 + c] = bs2; Bsh[w][c] = bs2; }
    __syncthreads();
    float acc = 0.f;
#pragma unroll
    for (int dd2 = 0; dd2 < 16; dd2++) {
        int d = h * 16 + dd2;
        acc += Bsh[w][d] * wmixT[d * 32 + c];
    }
    acc += __shfl_xor(acc, 32);
    if (h == 0) ba1q[n * 32 + c] = f2b(acc);
    if (t == 0) atomicAdd(&out[(blockIdx.x * 4) >> 11], ev[0] + ev[1] + ev[2] + ev[3]);
}

// ---------------- backward l=1 fused: barS1 -> barA0 -> pk (full packed force operands) ----------------
// pk layout: q.x lo=s1 hi=s2 ; q.y lo=ba0 hi=ba1 ; q.z lo=s0
__global__ __launch_bounds__(256) void k_B1F(
    const unsigned short* __restrict__ ba1q, const float* __restrict__ barS2,
    const unsigned short* __restrict__ s1q, const unsigned short* __restrict__ s2q,
    const int* __restrict__ at, const float* __restrict__ W_embed,
    const uint4* __restrict__ basisq, const int* __restrict__ cnt,
    const int2* __restrict__ inc,
    const float* __restrict__ Wrad1, const float* __restrict__ Wmix0,
    uint4* __restrict__ pk)
{
    __shared__ float wmixT[1024];   // Wmix0 transposed: [d][c]
    __shared__ float Bsh[4][32];
    __shared__ float We[128];
    int t = threadIdx.x;
    for (int i = t; i < 1024; i += 256) wmixT[(i & 31) * 32 + (i >> 5)] = Wmix0[i];
    if (t < 128) We[t] = W_embed[t];
    int w = t >> 6, lane = t & 63, c = lane & 31, h = lane >> 5;
    int n = blockIdx.x * 4 + w;
    float wr[8];
#pragma unroll
    for (int bb = 0; bb < 8; bb++) wr[bb] = Wrad1[bb * 128 + c * 4];

    int cn = min(cnt[n], CAP);
    int h1 = (cn + 1) >> 1;
    int base = n * CAP;
    int j    = base + (h ? h1 : 0);
    int jend = base + (h ? cn : h1);
    float A = 0.f;
    for (; j + 3 < jend; j += 4) {
        int2 e0 = inc[j], e1 = inc[j+1], e2 = inc[j+2], e3 = inc[j+3];
        uint4 b0 = basisq[e0.x], b1 = basisq[e1.x], b2 = basisq[e2.x], b3 = basisq[e3.x];
        A += dot8q(b0, wr) * b2f(ba1q[(e0.y >> 1) * 32 + c])
           + dot8q(b1, wr) * b2f(ba1q[(e1.y >> 1) * 32 + c])
           + dot8q(b2, wr) * b2f(ba1q[(e2.y >> 1) * 32 + c])
           + dot8q(b3, wr) * b2f(ba1q[(e3.y >> 1) * 32 + c]);
    }
    for (; j < jend; ++j) {
        int2 e0 = inc[j];
        A += dot8q(basisq[e0.x], wr) * b2f(ba1q[(e0.y >> 1) * 32 + c]);
    }
    A += __shfl_xor(A, 32);
    float bs1 = barS2[n * 32 + c] + A;
    if (h == 0) Bsh[w][c] = bs1;
    __syncthreads();
    float acc = 0.f;
#pragma unroll
    for (int dd2 = 0; dd2 < 16; dd2++) {
        int d = h * 16 + dd2;
        acc += Bsh[w][d] * wmixT[d * 32 + c];
    }
    acc += __shfl_xor(acc, 32);     // barA0[n,c]
    if (h == 0) {
        int n32c = n * 32 + c;
        uint4 v;
        v.x = (unsigned)s1q[n32c]  | ((unsigned)s2q[n32c] << 16);
        v.y = (unsigned)f2b(acc)   | ((unsigned)ba1q[n32c] << 16);
        v.z = (unsigned)f2b(We[at[n] * 32 + c]);
        v.w = 0;
        pk[n32c] = v;
    }
}

// ---------------- forces: single uint4 gather per neighbor, 4-way unroll ----------------
__global__ __launch_bounds__(256) void k_force(
    const uint4* __restrict__ pk, const float* __restrict__ g2,
    const uint4* __restrict__ dbq, const float4* __restrict__ unit,
    const int* __restrict__ cnt, const int2* __restrict__ inc,
    const float* __restrict__ W_rad, float* __restrict__ out)
{
    int t = threadIdx.x;
    int w = t >> 6, lane = t & 63, c = lane & 31, h = lane >> 5;
    int n = blockIdx.x * 4 + w;
    float wr0[8], wr1[8], wr2[8];
#pragma unroll
    for (int bb = 0; bb < 8; bb++) {
        wr0[bb] = W_rad[0 * 1024 + bb * 128 + c * 4];
        wr1[bb] = W_rad[1 * 1024 + bb * 128 + c * 4];
        wr2[bb] = W_rad[2 * 1024 + bb * 128 + c * 4];
    }
    uint4 mq = pk[n * 32 + c];
    float ms1 = blo(mq.x), ms2 = bhi(mq.x);
    float mb0 = blo(mq.y), mb1 = bhi(mq.y);
    float ms0 = blo(mq.z);
    float g2c = g2[c];

    float Fx = 0.f, Fy = 0.f, Fz = 0.f;
    int cn = min(cnt[n], CAP);
    int h1 = (cn + 1) >> 1;
    int base = n * CAP;
    int j    = base + (h ? h1 : 0);
    int jend = base + (h ? cn : h1);

    for (; j + 3 < jend; j += 4) {
        int2 e0 = inc[j], e1 = inc[j+1], e2 = inc[j+2], e3 = inc[j+3];
        uint4 q0 = pk[(e0.y >> 1) * 32 + c], q1 = pk[(e1.y >> 1) * 32 + c];
        uint4 q2 = pk[(e2.y >> 1) * 32 + c], q3 = pk[(e3.y >> 1) * 32 + c];
        uint4 d0 = dbq[e0.x], d1 = dbq[e1.x], d2 = dbq[e2.x], d3 = dbq[e3.x];
        float4 v0 = unit[e0.x], v1 = unit[e1.x], v2 = unit[e2.x], v3 = unit[e3.x];
        float tc0 = dot8q(d0, wr0) * (mb0 * blo(q0.z) + blo(q0.y) * ms0)
                  + dot8q(d0, wr1) * (mb1 * blo(q0.x) + bhi(q0.y) * ms1)
                  + dot8q(d0, wr2) * g2c * (bhi(q0.x) + ms2);
        tc0 = (e0.y & 1) ? -tc0 : tc0;
        Fx += tc0 * v0.x; Fy += tc0 * v0.y; Fz += tc0 * v0.z;
        float tc1 = dot8q(d1, wr0) * (mb0 * blo(q1.z) + blo(q1.y) * ms0)
                  + dot8q(d1, wr1) * (mb1 * blo(q1.x) + bhi(q1.y) * ms1)
                  + dot8q(d1, wr2) * g2c * (bhi(q1.x) + ms2);
        tc1 = (e1.y & 1) ? -tc1 : tc1;
        Fx += tc1 * v1.x; Fy += tc1 * v1.y; Fz += tc1 * v1.z;
        float tc2 = dot8q(d2, wr0) * (mb0 * blo(q2.z) + blo(q2.y) * ms0)
                  + dot8q(d2, wr1) * (mb1 * blo(q2.x) + bhi(q2.y) * ms1)
                  + dot8q(d2, wr2) * g2c * (bhi(q2.x) + ms2);
        tc2 = (e2.y & 1) ? -tc2 : tc2;
        Fx += tc2 * v2.x; Fy += tc2 * v2.y; Fz += tc2 * v2.z;
        float tc3 = dot8q(d3, wr0) * (mb0 * blo(q3.z) + blo(q3.y) * ms0)
                  + dot8q(d3, wr1) * (mb1 * blo(q3.x) + bhi(q3.y) * ms1)
                  + dot8q(d3, wr2) * g2c * (bhi(q3.x) + ms2);
        tc3 = (e3.y & 1) ? -tc3 : tc3;
        Fx += tc3 * v3.x; Fy += tc3 * v3.y; Fz += tc3 * v3.z;
    }
    for (; j < jend; ++j) {
        int2 e0 = inc[j];
        uint4 q0 = pk[(e0.y >> 1) * 32 + c];
        uint4 d0 = dbq[e0.x];
        float4 v0 = unit[e0.x];
        float tc0 = dot8q(d0, wr0) * (mb0 * blo(q0.z) + blo(q0.y) * ms0)
                  + dot8q(d0, wr1) * (mb1 * blo(q0.x) + bhi(q0.y) * ms1)
                  + dot8q(d0, wr2) * g2c * (bhi(q0.x) + ms2);
        tc0 = (e0.y & 1) ? -tc0 : tc0;
        Fx += tc0 * v0.x; Fy += tc0 * v0.y; Fz += tc0 * v0.z;
    }
#pragma unroll
    for (int o = 1; o <= 32; o <<= 1) {
        Fx += __shfl_xor(Fx, o);
        Fy += __shfl_xor(Fy, o);
        Fz += __shfl_xor(Fz, o);
    }
    if (lane == 0) {
        out[8 + n * 3 + 0] = Fx;
        out[8 + n * 3 + 1] = Fy;
        out[8 + n * 3 + 2] = Fz;
    }
}

extern "C" void kernel_launch(void* const* d_in, const int* in_sizes, int n_in,
                              void* d_out, int out_size, void* d_ws, size_t ws_size,
                              hipStream_t stream)
{
    const float* pos     = (const float*)d_in[0];
    const int*   eidx    = (const int*)  d_in[1];
    const float* cell    = (const float*)d_in[2];
    const int*   at      = (const int*)  d_in[3];
    const float* W_embed = (const float*)d_in[4];
    const float* W_rad   = (const float*)d_in[5];
    const float* W_mix   = (const float*)d_in[6];
    const float* w_out   = (const float*)d_in[7];
    const int*   co      = (const int*)  d_in[8];

    char* p = (char*)d_ws;
    auto carve = [&](size_t bytes) -> char* {
        char* r = p;
        p += (bytes + 255) & ~(size_t)255;
        return r;
    };
    uint4*          basisq = (uint4*)          carve((size_t)FE * 16);
    uint4*          dbq    = (uint4*)          carve((size_t)FE * 16);
    float4*         unit   = (float4*)         carve((size_t)FE * 16);
    unsigned short* s1q    = (unsigned short*) carve((size_t)FN * 32 * 2);
    unsigned short* s2q    = (unsigned short*) carve((size_t)FN * 32 * 2);
    unsigned short* ba1q   = (unsigned short*) carve((size_t)FN * 32 * 2);
    float*          barS2  = (float*)          carve((size_t)FN * 32 * 4);
    uint4*          pk     = (uint4*)          carve((size_t)FN * 32 * 16);
    float*          g2     = (float*)          carve(32 * 4);
    int*            cnt    = (int*)            carve((size_t)FN * 4);
    int2*           inc    = (int2*)           carve((size_t)FN * CAP * 8);

    hipMemsetAsync(cnt, 0, (size_t)FN * 4, stream);
    hipMemsetAsync(d_out, 0, F_NUM * 4, stream);   // energy accumulators

    k_edges<<<FE / 256, 256, 0, stream>>>(pos, eidx, cell, co, basisq, dbq, unit, cnt, inc);
    k_g2<<<1, 32, 0, stream>>>(w_out, W_mix + 2 * 1024, g2);

    // forward
    k_L<true><<<FN / 4, 256, 0, stream>>>(nullptr, at, W_embed, s1q, basisq, cnt, inc,
                                          W_rad + 0 * 1024, W_mix + 0 * 1024);
    k_L<false><<<FN / 4, 256, 0, stream>>>(s1q, at, W_embed, s2q, basisq, cnt, inc,
                                           W_rad + 1 * 1024, W_mix + 1 * 1024);
    // layer 2 + energy + barS2 + barA1
    k_L2E<<<FN / 4, 256, 0, stream>>>(s2q, basisq, cnt, inc, W_rad + 2 * 1024,
                                      W_mix + 1 * 1024, w_out, g2, barS2, ba1q, (float*)d_out);
    // backward l=1 + barA0 + pack
    k_B1F<<<FN / 4, 256, 0, stream>>>(ba1q, barS2, s1q, s2q, at, W_embed, basisq, cnt, inc,
                                      W_rad + 1 * 1024, W_mix + 0 * 1024, pk);
    // forces
    k_force<<<FN / 4, 256, 0, stream>>>(pk, g2, dbq, unit, cnt, inc, W_rad, (float*)d_out);
}

// Round 6
// 250.298 us; speedup vs baseline: 1.8068x; 1.1515x over previous
//
#include <hip/hip_runtime.h>
#include <math.h>

#define F_NUM 8
#define N_AT 2048
#define E_EDGE 32768
#define FE (F_NUM*E_EDGE)   // 262144 base edges
#define FN (F_NUM*N_AT)     // 16384 atoms
#define CAP 72              // per-atom incidence capacity (avg 32, Poisson)
#define PI_F 3.14159265358979f

__device__ __forceinline__ unsigned short f2b(float x) {
    unsigned int u = __float_as_uint(x);
    u += 0x8000u;
    return (unsigned short)(u >> 16);
}
__device__ __forceinline__ float blo(unsigned int u) { return __uint_as_float(u << 16); }
__device__ __forceinline__ float bhi(unsigned int u) { return __uint_as_float(u & 0xffff0000u); }
__device__ __forceinline__ float b2f(unsigned short u) { return __uint_as_float((unsigned)u << 16); }

// dot of 8 bf16-packed values (uint4) with 8 f32 weights
__device__ __forceinline__ float dot8q(uint4 q, const float* w) {
    return blo(q.x)*w[0] + bhi(q.x)*w[1] + blo(q.y)*w[2] + bhi(q.y)*w[3]
         + blo(q.z)*w[4] + bhi(q.z)*w[5] + blo(q.w)*w[6] + bhi(q.w)*w[7];
}

// ---------------- edges: geometry + bf16 basis/dbasis + unit + direct scatter into padded lists ----------------
__global__ __launch_bounds__(256) void k_edges(
    const float* __restrict__ pos, const int* __restrict__ eidx,
    const float* __restrict__ cell, const int* __restrict__ co_p,
    uint4* __restrict__ basisq, uint4* __restrict__ dbasisq,
    float4* __restrict__ unit, int* __restrict__ cnt, int2* __restrict__ inc)
{
    int k = blockIdx.x * 256 + threadIdx.x;
    if (k >= FE) return;
    int f = k >> 15;
    int e = k & (E_EDGE - 1);
    int a = eidx[f * 2 * E_EDGE + e] + f * N_AT;
    int b = eidx[f * 2 * E_EDGE + E_EDGE + e] + f * N_AT;
    float co = (float)co_p[0];

    float vec[3];
#pragma unroll
    for (int d = 0; d < 3; d++) {
        float v  = pos[3 * b + d] - pos[3 * a + d];
        float cl = cell[3 * f + d];
        float sh = cl * ((v < -co ? 1.f : 0.f) - (v > co ? 1.f : 0.f));
        vec[d] = v + sh;
    }
    float r2   = vec[0]*vec[0] + vec[1]*vec[1] + vec[2]*vec[2] + 1e-12f;
    float r    = sqrtf(r2);
    float rinv = 1.f / r;
    unit[k] = make_float4(vec[0]*rinv, vec[1]*rinv, vec[2]*rinv, 0.f);

    float x = r * (1.f / 6.f);           // R_MAX = 6
    float env = 0.f, denv = 0.f;
    if (x < 1.f) {
        float x2 = x*x, x3 = x2*x, x5 = x2*x3, x6 = x5*x, x7 = x6*x, x8 = x7*x;
        env  = 1.f - 28.f*x6 + 48.f*x7 - 21.f*x8;
        denv = -168.f*x5 + 336.f*x6 - 168.f*x7;
    }
    float s1, c1;
    sincosf(PI_F * x, &s1, &c1);
    float sn = s1, cn = c1;
    const float C0 = 0.57735026919f;     // sqrt(2/6)
    float bs[8], db[8];
#pragma unroll
    for (int n = 1; n <= 8; n++) {
        float kn  = (float)n * PI_F * (1.f / 6.f);
        float bes = C0 * sn * rinv;
        bs[n-1] = bes * env;
        db[n-1] = C0 * rinv * (kn * cn - sn * rinv) * env + bes * denv * (1.f / 6.f);
        float sn2 = sn * c1 + cn * s1;
        float cn2 = cn * c1 - sn * s1;
        sn = sn2; cn = cn2;
    }
    uint4 B, D;
    B.x = (unsigned)f2b(bs[0]) | ((unsigned)f2b(bs[1]) << 16);
    B.y = (unsigned)f2b(bs[2]) | ((unsigned)f2b(bs[3]) << 16);
    B.z = (unsigned)f2b(bs[4]) | ((unsigned)f2b(bs[5]) << 16);
    B.w = (unsigned)f2b(bs[6]) | ((unsigned)f2b(bs[7]) << 16);
    D.x = (unsigned)f2b(db[0]) | ((unsigned)f2b(db[1]) << 16);
    D.y = (unsigned)f2b(db[2]) | ((unsigned)f2b(db[3]) << 16);
    D.z = (unsigned)f2b(db[4]) | ((unsigned)f2b(db[5]) << 16);
    D.w = (unsigned)f2b(db[6]) | ((unsigned)f2b(db[7]) << 16);
    basisq[k] = B;
    dbasisq[k] = D;

    int sa = atomicAdd(&cnt[a], 1);
    if (sa < CAP) inc[a * CAP + sa] = make_int2(k, (b << 1));        // n==a: +unit
    int sb = atomicAdd(&cnt[b], 1);
    if (sb < CAP) inc[b * CAP + sb] = make_int2(k, (a << 1) | 1);    // n==b: -unit
}

// ---------------- g2[c] = sum_d w_out[d] * Wmix2[c,d] ----------------
__global__ void k_g2(const float* __restrict__ w_out, const float* __restrict__ Wmix2, float* __restrict__ g2)
{
    int c = threadIdx.x;
    float acc = 0.f;
#pragma unroll
    for (int d = 0; d < 32; d++) acc += w_out[d] * Wmix2[c * 32 + d];
    g2[c] = acc;
}

// ---------------- forward layer; features stored/gathered as bf16 rows ----------------
template<bool L0>
__global__ __launch_bounds__(256, 8) void k_L(
    const unsigned short* __restrict__ slq, const int* __restrict__ at,
    const float* __restrict__ W_embed, unsigned short* __restrict__ soq,
    const uint4* __restrict__ basisq, const int* __restrict__ cnt,
    const int2* __restrict__ inc,
    const float* __restrict__ Wrad_l, const float* __restrict__ Wmix_l)
{
    __shared__ float wmix[1024];
    __shared__ float Ash[4][32];
    __shared__ float We[128];
    int t = threadIdx.x;
    for (int i = t; i < 1024; i += 256) wmix[i] = Wmix_l[i];
    if (L0 && t < 128) We[t] = W_embed[t];
    int w = t >> 6, lane = t & 63, c = lane & 31, h = lane >> 5;
    int n = blockIdx.x * 4 + w;
    float wr[8];
#pragma unroll
    for (int bb = 0; bb < 8; bb++) wr[bb] = Wrad_l[bb * 128 + c * 4];
    __syncthreads();

    int cn = min(cnt[n], CAP);
    int h1 = (cn + 1) >> 1;
    int base = n * CAP;
    int j    = base + (h ? h1 : 0);
    int jend = base + (h ? cn : h1);
    float A = 0.f;
    for (; j + 3 < jend; j += 4) {
        int2 e0 = inc[j], e1 = inc[j+1], e2 = inc[j+2], e3 = inc[j+3];
        uint4 b0 = basisq[e0.x], b1 = basisq[e1.x], b2 = basisq[e2.x], b3 = basisq[e3.x];
        float sv0, sv1, sv2, sv3;
        if (L0) {
            sv0 = We[at[e0.y >> 1] * 32 + c];
            sv1 = We[at[e1.y >> 1] * 32 + c];
            sv2 = We[at[e2.y >> 1] * 32 + c];
            sv3 = We[at[e3.y >> 1] * 32 + c];
        } else {
            sv0 = b2f(slq[(e0.y >> 1) * 32 + c]);
            sv1 = b2f(slq[(e1.y >> 1) * 32 + c]);
            sv2 = b2f(slq[(e2.y >> 1) * 32 + c]);
            sv3 = b2f(slq[(e3.y >> 1) * 32 + c]);
        }
        A += dot8q(b0, wr) * sv0 + dot8q(b1, wr) * sv1
           + dot8q(b2, wr) * sv2 + dot8q(b3, wr) * sv3;
    }
    for (; j < jend; ++j) {
        int2 e0 = inc[j];
        uint4 b0 = basisq[e0.x];
        float sv0 = L0 ? We[at[e0.y >> 1] * 32 + c] : b2f(slq[(e0.y >> 1) * 32 + c]);
        A += dot8q(b0, wr) * sv0;
    }
    A += __shfl_xor(A, 32);
    if (h == 0) Ash[w][c] = A;
    __syncthreads();
    float base_s = L0 ? We[at[n] * 32 + c] : b2f(slq[n * 32 + c]);
    float acc = 0.f;
#pragma unroll
    for (int cc2 = 0; cc2 < 16; cc2++) {
        int cc = h * 16 + cc2;
        acc += Ash[w][cc] * wmix[cc * 32 + c];
    }
    acc += __shfl_xor(acc, 32);
    if (h == 0) soq[n * 32 + c] = f2b(base_s + acc);
}

// ---------------- layer 2 fused: energy + barS2 + barA1(bf16) ----------------
__global__ __launch_bounds__(256, 8) void k_L2E(
    const unsigned short* __restrict__ s2q, const uint4* __restrict__ basisq,
    const int* __restrict__ cnt, const int2* __restrict__ inc,
    const float* __restrict__ Wrad2, const float* __restrict__ Wmix1,
    const float* __restrict__ w_out, const float* __restrict__ g2,
    float* __restrict__ barS2, unsigned short* __restrict__ ba1q, float* __restrict__ out)
{
    __shared__ float wmixT[1024];   // Wmix1 transposed: [d][c]
    __shared__ float Bsh[4][32];
    __shared__ float ev[4];
    int t = threadIdx.x;
    for (int i = t; i < 1024; i += 256) wmixT[(i & 31) * 32 + (i >> 5)] = Wmix1[i];
    int w = t >> 6, lane = t & 63, c = lane & 31, h = lane >> 5;
    int n = blockIdx.x * 4 + w;
    float wr[8];
#pragma unroll
    for (int bb = 0; bb < 8; bb++) wr[bb] = Wrad2[bb * 128 + c * 4];

    int cn = min(cnt[n], CAP);
    int h1 = (cn + 1) >> 1;
    int base = n * CAP;
    int j    = base + (h ? h1 : 0);
    int jend = base + (h ? cn : h1);
    float A = 0.f, S = 0.f;
    for (; j + 3 < jend; j += 4) {
        int2 e0 = inc[j], e1 = inc[j+1], e2 = inc[j+2], e3 = inc[j+3];
        uint4 b0 = basisq[e0.x], b1 = basisq[e1.x], b2 = basisq[e2.x], b3 = basisq[e3.x];
        float r0 = dot8q(b0, wr), r1 = dot8q(b1, wr), r2 = dot8q(b2, wr), r3 = dot8q(b3, wr);
        A += r0 * b2f(s2q[(e0.y >> 1) * 32 + c]) + r1 * b2f(s2q[(e1.y >> 1) * 32 + c])
           + r2 * b2f(s2q[(e2.y >> 1) * 32 + c]) + r3 * b2f(s2q[(e3.y >> 1) * 32 + c]);
        S += r0 + r1 + r2 + r3;
    }
    for (; j < jend; ++j) {
        int2 e0 = inc[j];
        float r0 = dot8q(basisq[e0.x], wr);
        A += r0 * b2f(s2q[(e0.y >> 1) * 32 + c]);
        S += r0;
    }
    A += __shfl_xor(A, 32);
    S += __shfl_xor(S, 32);

    float woc = w_out[c], g2c = g2[c];
    float s2n = b2f(s2q[n * 32 + c]);
    float te = s2n * woc + A * g2c;     // energy contribution of atom n (per channel)
#pragma unroll
    for (int o = 1; o <= 16; o <<= 1) te += __shfl_xor(te, o);
    if (lane == 0) ev[w] = te;
    float bs2 = woc + g2c * S;
    if (h == 0) { barS2[n * 32 + c] = bs2; Bsh[w][c] = bs2; }
    __syncthreads();
    float acc = 0.f;
#pragma unroll
    for (int dd2 = 0; dd2 < 16; dd2++) {
        int d = h * 16 + dd2;
        acc += Bsh[w][d] * wmixT[d * 32 + c];
    }
    acc += __shfl_xor(acc, 32);
    if (h == 0) ba1q[n * 32 + c] = f2b(acc);
    if (t == 0) atomicAdd(&out[(blockIdx.x * 4) >> 11], ev[0] + ev[1] + ev[2] + ev[3]);
}

// ---------------- backward l=1 fused: barS1 -> barA0 -> pk (full packed force operands) ----------------
// pk layout: q.x lo=s1 hi=s2 ; q.y lo=ba0 hi=ba1 ; q.z lo=s0
__global__ __launch_bounds__(256, 8) void k_B1F(
    const unsigned short* __restrict__ ba1q, const float* __restrict__ barS2,
    const unsigned short* __restrict__ s1q, const unsigned short* __restrict__ s2q,
    const int* __restrict__ at, const float* __restrict__ W_embed,
    const uint4* __restrict__ basisq, const int* __restrict__ cnt,
    const int2* __restrict__ inc,
    const float* __restrict__ Wrad1, const float* __restrict__ Wmix0,
    uint4* __restrict__ pk)
{
    __shared__ float wmixT[1024];   // Wmix0 transposed: [d][c]
    __shared__ float Bsh[4][32];
    __shared__ float We[128];
    int t = threadIdx.x;
    for (int i = t; i < 1024; i += 256) wmixT[(i & 31) * 32 + (i >> 5)] = Wmix0[i];
    if (t < 128) We[t] = W_embed[t];
    int w = t >> 6, lane = t & 63, c = lane & 31, h = lane >> 5;
    int n = blockIdx.x * 4 + w;
    float wr[8];
#pragma unroll
    for (int bb = 0; bb < 8; bb++) wr[bb] = Wrad1[bb * 128 + c * 4];

    int cn = min(cnt[n], CAP);
    int h1 = (cn + 1) >> 1;
    int base = n * CAP;
    int j    = base + (h ? h1 : 0);
    int jend = base + (h ? cn : h1);
    float A = 0.f;
    for (; j + 3 < jend; j += 4) {
        int2 e0 = inc[j], e1 = inc[j+1], e2 = inc[j+2], e3 = inc[j+3];
        uint4 b0 = basisq[e0.x], b1 = basisq[e1.x], b2 = basisq[e2.x], b3 = basisq[e3.x];
        A += dot8q(b0, wr) * b2f(ba1q[(e0.y >> 1) * 32 + c])
           + dot8q(b1, wr) * b2f(ba1q[(e1.y >> 1) * 32 + c])
           + dot8q(b2, wr) * b2f(ba1q[(e2.y >> 1) * 32 + c])
           + dot8q(b3, wr) * b2f(ba1q[(e3.y >> 1) * 32 + c]);
    }
    for (; j < jend; ++j) {
        int2 e0 = inc[j];
        A += dot8q(basisq[e0.x], wr) * b2f(ba1q[(e0.y >> 1) * 32 + c]);
    }
    A += __shfl_xor(A, 32);
    float bs1 = barS2[n * 32 + c] + A;
    if (h == 0) Bsh[w][c] = bs1;
    __syncthreads();
    float acc = 0.f;
#pragma unroll
    for (int dd2 = 0; dd2 < 16; dd2++) {
        int d = h * 16 + dd2;
        acc += Bsh[w][d] * wmixT[d * 32 + c];
    }
    acc += __shfl_xor(acc, 32);     // barA0[n,c]
    if (h == 0) {
        int n32c = n * 32 + c;
        uint4 v;
        v.x = (unsigned)s1q[n32c]  | ((unsigned)s2q[n32c] << 16);
        v.y = (unsigned)f2b(acc)   | ((unsigned)ba1q[n32c] << 16);
        v.z = (unsigned)f2b(We[at[n] * 32 + c]);
        v.w = 0;
        pk[n32c] = v;
    }
}

// ---------------- forces, EDGE-PARALLEL: one 32-lane group per edge, coalesced pk rows ----------------
// dEdr_k = sum_c [ dR0*(ba0[a]s0[b]+ba0[b]s0[a]) + dR1*(ba1[a]s1[b]+ba1[b]s1[a]) + dR2*g2*(s2[a]+s2[b]) ]
// F[a] += dEdr*unit ; F[b] -= dEdr*unit   (atomicAdd, out zero-initialized)
#define EPG 8   // edges per 32-lane group
__global__ __launch_bounds__(256, 8) void k_force_e(
    const uint4* __restrict__ pk, const float* __restrict__ g2,
    const uint4* __restrict__ dbq, const float4* __restrict__ unit,
    const int* __restrict__ eidx, const float* __restrict__ W_rad,
    float* __restrict__ out)
{
    int t = threadIdx.x;
    int g = t >> 5;             // group 0..7 in block
    int c = t & 31;
    float wr0[8], wr1[8], wr2[8];
#pragma unroll
    for (int bb = 0; bb < 8; bb++) {
        wr0[bb] = W_rad[0 * 1024 + bb * 128 + c * 4];
        wr1[bb] = W_rad[1 * 1024 + bb * 128 + c * 4];
        wr2[bb] = W_rad[2 * 1024 + bb * 128 + c * 4];
    }
    float g2c = g2[c];

    int kbase = (blockIdx.x * 8 + g) * EPG;
#pragma unroll 2
    for (int kk = 0; kk < EPG; ++kk) {
        int k = kbase + kk;
        int f = k >> 15;
        int e = k & (E_EDGE - 1);
        int a = eidx[f * 2 * E_EDGE + e] + f * N_AT;
        int b = eidx[f * 2 * E_EDGE + E_EDGE + e] + f * N_AT;
        uint4 d  = dbq[k];
        uint4 qa = pk[a * 32 + c];
        uint4 qb = pk[b * 32 + c];
        float dR0 = dot8q(d, wr0), dR1 = dot8q(d, wr1), dR2 = dot8q(d, wr2);
        float tc = dR0 * (blo(qa.y) * blo(qb.z) + blo(qb.y) * blo(qa.z))
                 + dR1 * (bhi(qa.y) * blo(qb.x) + bhi(qb.y) * blo(qa.x))
                 + dR2 * g2c * (bhi(qa.x) + bhi(qb.x));
#pragma unroll
        for (int o = 1; o <= 16; o <<= 1) tc += __shfl_xor(tc, o, 32);
        float4 uv = unit[k];
        if (c < 3) {
            float uc = (c == 0) ? uv.x : (c == 1) ? uv.y : uv.z;
            atomicAdd(&out[8 + a * 3 + c], tc * uc);
        } else if (c < 6) {
            int d3 = c - 3;
            float uc = (d3 == 0) ? uv.x : (d3 == 1) ? uv.y : uv.z;
            atomicAdd(&out[8 + b * 3 + d3], -tc * uc);
        }
    }
}

extern "C" void kernel_launch(void* const* d_in, const int* in_sizes, int n_in,
                              void* d_out, int out_size, void* d_ws, size_t ws_size,
                              hipStream_t stream)
{
    const float* pos     = (const float*)d_in[0];
    const int*   eidx    = (const int*)  d_in[1];
    const float* cell    = (const float*)d_in[2];
    const int*   at      = (const int*)  d_in[3];
    const float* W_embed = (const float*)d_in[4];
    const float* W_rad   = (const float*)d_in[5];
    const float* W_mix   = (const float*)d_in[6];
    const float* w_out   = (const float*)d_in[7];
    const int*   co      = (const int*)  d_in[8];

    char* p = (char*)d_ws;
    auto carve = [&](size_t bytes) -> char* {
        char* r = p;
        p += (bytes + 255) & ~(size_t)255;
        return r;
    };
    uint4*          basisq = (uint4*)          carve((size_t)FE * 16);
    uint4*          dbq    = (uint4*)          carve((size_t)FE * 16);
    float4*         unit   = (float4*)         carve((size_t)FE * 16);
    unsigned short* s1q    = (unsigned short*) carve((size_t)FN * 32 * 2);
    unsigned short* s2q    = (unsigned short*) carve((size_t)FN * 32 * 2);
    unsigned short* ba1q   = (unsigned short*) carve((size_t)FN * 32 * 2);
    float*          barS2  = (float*)          carve((size_t)FN * 32 * 4);
    uint4*          pk     = (uint4*)          carve((size_t)FN * 32 * 16);
    float*          g2     = (float*)          carve(32 * 4);
    int*            cnt    = (int*)            carve((size_t)FN * 4);
    int2*           inc    = (int2*)           carve((size_t)FN * CAP * 8);

    hipMemsetAsync(cnt, 0, (size_t)FN * 4, stream);
    hipMemsetAsync(d_out, 0, (size_t)(8 + FN * 3) * 4, stream);  // energy + force accumulators

    k_edges<<<FE / 256, 256, 0, stream>>>(pos, eidx, cell, co, basisq, dbq, unit, cnt, inc);
    k_g2<<<1, 32, 0, stream>>>(w_out, W_mix + 2 * 1024, g2);

    // forward
    k_L<true><<<FN / 4, 256, 0, stream>>>(nullptr, at, W_embed, s1q, basisq, cnt, inc,
                                          W_rad + 0 * 1024, W_mix + 0 * 1024);
    k_L<false><<<FN / 4, 256, 0, stream>>>(s1q, at, W_embed, s2q, basisq, cnt, inc,
                                           W_rad + 1 * 1024, W_mix + 1 * 1024);
    // layer 2 + energy + barS2 + barA1
    k_L2E<<<FN / 4, 256, 0, stream>>>(s2q, basisq, cnt, inc, W_rad + 2 * 1024,
                                      W_mix + 1 * 1024, w_out, g2, barS2, ba1q, (float*)d_out);
    // backward l=1 + barA0 + pack
    k_B1F<<<FN / 4, 256, 0, stream>>>(ba1q, barS2, s1q, s2q, at, W_embed, basisq, cnt, inc,
                                      W_rad + 1 * 1024, W_mix + 0 * 1024, pk);
    // forces (edge-parallel, atomic accumulation)
    k_force_e<<<FE / (8 * EPG), 256, 0, stream>>>(pk, g2, dbq, unit, eidx, W_rad, (float*)d_out);
}

// Round 7
// 240.652 us; speedup vs baseline: 1.8792x; 1.0401x over previous
//
#include <hip/hip_runtime.h>
#include <math.h>

#define F_NUM 8
#define N_AT 2048
#define E_EDGE 32768
#define FE (F_NUM*E_EDGE)   // 262144 base edges
#define FN (F_NUM*N_AT)     // 16384 atoms
#define CAP 72              // per-atom incidence capacity (avg 32, Poisson)
#define PI_F 3.14159265358979f

__device__ __forceinline__ unsigned short f2b(float x) {
    unsigned int u = __float_as_uint(x);
    u += 0x8000u;
    return (unsigned short)(u >> 16);
}
__device__ __forceinline__ float blo(unsigned int u) { return __uint_as_float(u << 16); }
__device__ __forceinline__ float bhi(unsigned int u) { return __uint_as_float(u & 0xffff0000u); }
__device__ __forceinline__ float b2f(unsigned short u) { return __uint_as_float((unsigned)u << 16); }

// dot of 8 bf16-packed values (uint4) with 8 f32 weights
__device__ __forceinline__ float dot8q(uint4 q, const float* w) {
    return blo(q.x)*w[0] + bhi(q.x)*w[1] + blo(q.y)*w[2] + bhi(q.y)*w[3]
         + blo(q.z)*w[4] + bhi(q.z)*w[5] + blo(q.w)*w[6] + bhi(q.w)*w[7];
}

// ---------------- edges: geometry, bf16 dbasis (edge order), bf16 basis + nb|type (incidence order) ----------------
__global__ __launch_bounds__(256) void k_edges(
    const float* __restrict__ pos, const int* __restrict__ eidx,
    const float* __restrict__ cell, const int* __restrict__ co_p,
    const int* __restrict__ at,
    uint4* __restrict__ dbq, float4* __restrict__ unit,
    int* __restrict__ cnt, int* __restrict__ nbq, uint4* __restrict__ binc)
{
    int k = blockIdx.x * 256 + threadIdx.x;
    if (k >= FE) return;
    int f = k >> 15;
    int e = k & (E_EDGE - 1);
    int a = eidx[f * 2 * E_EDGE + e] + f * N_AT;
    int b = eidx[f * 2 * E_EDGE + E_EDGE + e] + f * N_AT;
    int ta = at[a], tb = at[b];
    float co = (float)co_p[0];

    float vec[3];
#pragma unroll
    for (int d = 0; d < 3; d++) {
        float v  = pos[3 * b + d] - pos[3 * a + d];
        float cl = cell[3 * f + d];
        float sh = cl * ((v < -co ? 1.f : 0.f) - (v > co ? 1.f : 0.f));
        vec[d] = v + sh;
    }
    float r2   = vec[0]*vec[0] + vec[1]*vec[1] + vec[2]*vec[2] + 1e-12f;
    float r    = sqrtf(r2);
    float rinv = 1.f / r;
    unit[k] = make_float4(vec[0]*rinv, vec[1]*rinv, vec[2]*rinv, 0.f);

    float x = r * (1.f / 6.f);           // R_MAX = 6
    float env = 0.f, denv = 0.f;
    if (x < 1.f) {
        float x2 = x*x, x3 = x2*x, x5 = x2*x3, x6 = x5*x, x7 = x6*x, x8 = x7*x;
        env  = 1.f - 28.f*x6 + 48.f*x7 - 21.f*x8;
        denv = -168.f*x5 + 336.f*x6 - 168.f*x7;
    }
    float s1, c1;
    sincosf(PI_F * x, &s1, &c1);
    float sn = s1, cn = c1;
    const float C0 = 0.57735026919f;     // sqrt(2/6)
    float bs[8], db[8];
#pragma unroll
    for (int n = 1; n <= 8; n++) {
        float kn  = (float)n * PI_F * (1.f / 6.f);
        float bes = C0 * sn * rinv;
        bs[n-1] = bes * env;
        db[n-1] = C0 * rinv * (kn * cn - sn * rinv) * env + bes * denv * (1.f / 6.f);
        float sn2 = sn * c1 + cn * s1;
        float cn2 = cn * c1 - sn * s1;
        sn = sn2; cn = cn2;
    }
    uint4 B, D;
    B.x = (unsigned)f2b(bs[0]) | ((unsigned)f2b(bs[1]) << 16);
    B.y = (unsigned)f2b(bs[2]) | ((unsigned)f2b(bs[3]) << 16);
    B.z = (unsigned)f2b(bs[4]) | ((unsigned)f2b(bs[5]) << 16);
    B.w = (unsigned)f2b(bs[6]) | ((unsigned)f2b(bs[7]) << 16);
    D.x = (unsigned)f2b(db[0]) | ((unsigned)f2b(db[1]) << 16);
    D.y = (unsigned)f2b(db[2]) | ((unsigned)f2b(db[3]) << 16);
    D.z = (unsigned)f2b(db[4]) | ((unsigned)f2b(db[5]) << 16);
    D.w = (unsigned)f2b(db[6]) | ((unsigned)f2b(db[7]) << 16);
    dbq[k] = D;

    int sa = atomicAdd(&cnt[a], 1);
    if (sa < CAP) { nbq[a * CAP + sa] = (b << 2) | tb; binc[a * CAP + sa] = B; }
    int sb = atomicAdd(&cnt[b], 1);
    if (sb < CAP) { nbq[b * CAP + sb] = (a << 2) | ta; binc[b * CAP + sb] = B; }
}

// ---------------- g2[c] = sum_d w_out[d] * Wmix2[c,d] ----------------
__global__ void k_g2(const float* __restrict__ w_out, const float* __restrict__ Wmix2, float* __restrict__ g2)
{
    int c = threadIdx.x;
    float acc = 0.f;
#pragma unroll
    for (int d = 0; d < 32; d++) acc += w_out[d] * Wmix2[c * 32 + d];
    g2[c] = acc;
}

// ---------------- forward layer; incidence-ordered basis, no dependent basis load ----------------
template<bool L0>
__global__ __launch_bounds__(256, 8) void k_L(
    const unsigned short* __restrict__ slq, const float* __restrict__ W_embed,
    unsigned short* __restrict__ soq,
    const int* __restrict__ cnt, const int* __restrict__ nbq, const uint4* __restrict__ binc,
    const float* __restrict__ Wrad_l, const float* __restrict__ Wmix_l,
    const int* __restrict__ at)
{
    __shared__ float wmix[1024];
    __shared__ float Ash[4][32];
    __shared__ float We[128];
    int t = threadIdx.x;
    for (int i = t; i < 1024; i += 256) wmix[i] = Wmix_l[i];
    if (L0 && t < 128) We[t] = W_embed[t];
    int w = t >> 6, lane = t & 63, c = lane & 31, h = lane >> 5;
    int n = blockIdx.x * 4 + w;
    float wr[8];
#pragma unroll
    for (int bb = 0; bb < 8; bb++) wr[bb] = Wrad_l[bb * 128 + c * 4];
    __syncthreads();

    int cn = min(cnt[n], CAP);
    int h1 = (cn + 1) >> 1;
    int base = n * CAP;
    int j    = base + (h ? h1 : 0);
    int jend = base + (h ? cn : h1);
    float A = 0.f;
    for (; j + 3 < jend; j += 4) {
        int n0 = nbq[j], n1 = nbq[j+1], n2 = nbq[j+2], n3 = nbq[j+3];
        uint4 b0 = binc[j], b1 = binc[j+1], b2 = binc[j+2], b3 = binc[j+3];
        float sv0, sv1, sv2, sv3;
        if (L0) {
            sv0 = We[(n0 & 3) * 32 + c];
            sv1 = We[(n1 & 3) * 32 + c];
            sv2 = We[(n2 & 3) * 32 + c];
            sv3 = We[(n3 & 3) * 32 + c];
        } else {
            sv0 = b2f(slq[(n0 >> 2) * 32 + c]);
            sv1 = b2f(slq[(n1 >> 2) * 32 + c]);
            sv2 = b2f(slq[(n2 >> 2) * 32 + c]);
            sv3 = b2f(slq[(n3 >> 2) * 32 + c]);
        }
        A += dot8q(b0, wr) * sv0 + dot8q(b1, wr) * sv1
           + dot8q(b2, wr) * sv2 + dot8q(b3, wr) * sv3;
    }
    for (; j < jend; ++j) {
        int n0 = nbq[j];
        uint4 b0 = binc[j];
        float sv0 = L0 ? We[(n0 & 3) * 32 + c] : b2f(slq[(n0 >> 2) * 32 + c]);
        A += dot8q(b0, wr) * sv0;
    }
    A += __shfl_xor(A, 32);
    if (h == 0) Ash[w][c] = A;
    __syncthreads();
    float base_s = L0 ? We[at[n] * 32 + c] : b2f(slq[n * 32 + c]);
    float acc = 0.f;
#pragma unroll
    for (int cc2 = 0; cc2 < 16; cc2++) {
        int cc = h * 16 + cc2;
        acc += Ash[w][cc] * wmix[cc * 32 + c];
    }
    acc += __shfl_xor(acc, 32);
    if (h == 0) soq[n * 32 + c] = f2b(base_s + acc);
}

// ---------------- layer 2 fused: energy + barS2 + barA1(bf16) ----------------
__global__ __launch_bounds__(256, 8) void k_L2E(
    const unsigned short* __restrict__ s2q,
    const int* __restrict__ cnt, const int* __restrict__ nbq, const uint4* __restrict__ binc,
    const float* __restrict__ Wrad2, const float* __restrict__ Wmix1,
    const float* __restrict__ w_out, const float* __restrict__ g2,
    float* __restrict__ barS2, unsigned short* __restrict__ ba1q, float* __restrict__ out)
{
    __shared__ float wmixT[1056];   // Wmix1 transposed, stride 33 (bank-conflict-free)
    __shared__ float Bsh[4][32];
    __shared__ float ev[4];
    int t = threadIdx.x;
    for (int i = t; i < 1024; i += 256) wmixT[(i & 31) * 33 + (i >> 5)] = Wmix1[i];
    int w = t >> 6, lane = t & 63, c = lane & 31, h = lane >> 5;
    int n = blockIdx.x * 4 + w;
    float wr[8];
#pragma unroll
    for (int bb = 0; bb < 8; bb++) wr[bb] = Wrad2[bb * 128 + c * 4];

    int cn = min(cnt[n], CAP);
    int h1 = (cn + 1) >> 1;
    int base = n * CAP;
    int j    = base + (h ? h1 : 0);
    int jend = base + (h ? cn : h1);
    float A = 0.f, S = 0.f;
    for (; j + 3 < jend; j += 4) {
        int n0 = nbq[j], n1 = nbq[j+1], n2 = nbq[j+2], n3 = nbq[j+3];
        uint4 b0 = binc[j], b1 = binc[j+1], b2 = binc[j+2], b3 = binc[j+3];
        float r0 = dot8q(b0, wr), r1 = dot8q(b1, wr), r2 = dot8q(b2, wr), r3 = dot8q(b3, wr);
        A += r0 * b2f(s2q[(n0 >> 2) * 32 + c]) + r1 * b2f(s2q[(n1 >> 2) * 32 + c])
           + r2 * b2f(s2q[(n2 >> 2) * 32 + c]) + r3 * b2f(s2q[(n3 >> 2) * 32 + c]);
        S += r0 + r1 + r2 + r3;
    }
    for (; j < jend; ++j) {
        int n0 = nbq[j];
        float r0 = dot8q(binc[j], wr);
        A += r0 * b2f(s2q[(n0 >> 2) * 32 + c]);
        S += r0;
    }
    A += __shfl_xor(A, 32);
    S += __shfl_xor(S, 32);

    float woc = w_out[c], g2c = g2[c];
    float s2n = b2f(s2q[n * 32 + c]);
    float te = s2n * woc + A * g2c;     // energy contribution of atom n
#pragma unroll
    for (int o = 1; o <= 16; o <<= 1) te += __shfl_xor(te, o);
    if (lane == 0) ev[w] = te;
    float bs2 = woc + g2c * S;
    if (h == 0) { barS2[n * 32 + c] = bs2; Bsh[w][c] = bs2; }
    __syncthreads();
    float acc = 0.f;
#pragma unroll
    for (int dd2 = 0; dd2 < 16; dd2++) {
        int d = h * 16 + dd2;
        acc += Bsh[w][d] * wmixT[d * 33 + c];
    }
    acc += __shfl_xor(acc, 32);
    if (h == 0) ba1q[n * 32 + c] = f2b(acc);
    if (t == 0) atomicAdd(&out[(blockIdx.x * 4) >> 11], ev[0] + ev[1] + ev[2] + ev[3]);
}

// ---------------- backward l=1 fused: barS1 -> barA0 -> pk (uint2 packed force operands) ----------------
// pk layout: x = s1 | s2<<16 ; y = ba0 | ba1<<16
__global__ __launch_bounds__(256, 8) void k_B1F(
    const unsigned short* __restrict__ ba1q, const float* __restrict__ barS2,
    const unsigned short* __restrict__ s1q, const unsigned short* __restrict__ s2q,
    const int* __restrict__ cnt, const int* __restrict__ nbq, const uint4* __restrict__ binc,
    const float* __restrict__ Wrad1, const float* __restrict__ Wmix0,
    uint2* __restrict__ pk)
{
    __shared__ float wmixT[1056];   // Wmix0 transposed, stride 33
    __shared__ float Bsh[4][32];
    int t = threadIdx.x;
    for (int i = t; i < 1024; i += 256) wmixT[(i & 31) * 33 + (i >> 5)] = Wmix0[i];
    int w = t >> 6, lane = t & 63, c = lane & 31, h = lane >> 5;
    int n = blockIdx.x * 4 + w;
    float wr[8];
#pragma unroll
    for (int bb = 0; bb < 8; bb++) wr[bb] = Wrad1[bb * 128 + c * 4];

    int cn = min(cnt[n], CAP);
    int h1 = (cn + 1) >> 1;
    int base = n * CAP;
    int j    = base + (h ? h1 : 0);
    int jend = base + (h ? cn : h1);
    float A = 0.f;
    for (; j + 3 < jend; j += 4) {
        int n0 = nbq[j], n1 = nbq[j+1], n2 = nbq[j+2], n3 = nbq[j+3];
        uint4 b0 = binc[j], b1 = binc[j+1], b2 = binc[j+2], b3 = binc[j+3];
        A += dot8q(b0, wr) * b2f(ba1q[(n0 >> 2) * 32 + c])
           + dot8q(b1, wr) * b2f(ba1q[(n1 >> 2) * 32 + c])
           + dot8q(b2, wr) * b2f(ba1q[(n2 >> 2) * 32 + c])
           + dot8q(b3, wr) * b2f(ba1q[(n3 >> 2) * 32 + c]);
    }
    for (; j < jend; ++j) {
        int n0 = nbq[j];
        A += dot8q(binc[j], wr) * b2f(ba1q[(n0 >> 2) * 32 + c]);
    }
    A += __shfl_xor(A, 32);
    float bs1 = barS2[n * 32 + c] + A;
    if (h == 0) Bsh[w][c] = bs1;
    __syncthreads();
    float acc = 0.f;
#pragma unroll
    for (int dd2 = 0; dd2 < 16; dd2++) {
        int d = h * 16 + dd2;
        acc += Bsh[w][d] * wmixT[d * 33 + c];
    }
    acc += __shfl_xor(acc, 32);     // barA0[n,c]
    if (h == 0) {
        int n32c = n * 32 + c;
        uint2 v;
        v.x = (unsigned)s1q[n32c] | ((unsigned)s2q[n32c] << 16);
        v.y = (unsigned)f2b(acc)  | ((unsigned)ba1q[n32c] << 16);
        pk[n32c] = v;
    }
}

// ---------------- forces, EDGE-PARALLEL: one 32-lane group per edge; uint2 rows + LDS s0 ----------------
#define EPG 8   // edges per 32-lane group
__global__ __launch_bounds__(256, 8) void k_force_e(
    const uint2* __restrict__ pk, const float* __restrict__ g2,
    const uint4* __restrict__ dbq, const float4* __restrict__ unit,
    const int* __restrict__ eidx, const int* __restrict__ at,
    const float* __restrict__ W_embed, const float* __restrict__ W_rad,
    float* __restrict__ out)
{
    __shared__ float We[128];
    int t = threadIdx.x;
    if (t < 128) We[t] = W_embed[t];
    int g = t >> 5;             // group 0..7 in block
    int c = t & 31;
    float wr0[8], wr1[8], wr2[8];
#pragma unroll
    for (int bb = 0; bb < 8; bb++) {
        wr0[bb] = W_rad[0 * 1024 + bb * 128 + c * 4];
        wr1[bb] = W_rad[1 * 1024 + bb * 128 + c * 4];
        wr2[bb] = W_rad[2 * 1024 + bb * 128 + c * 4];
    }
    float g2c = g2[c];
    __syncthreads();

    int kbase = (blockIdx.x * 8 + g) * EPG;
#pragma unroll 2
    for (int kk = 0; kk < EPG; ++kk) {
        int k = kbase + kk;
        int f = k >> 15;
        int e = k & (E_EDGE - 1);
        int a = eidx[f * 2 * E_EDGE + e] + f * N_AT;
        int b = eidx[f * 2 * E_EDGE + E_EDGE + e] + f * N_AT;
        uint4 d  = dbq[k];
        uint2 qa = pk[a * 32 + c];
        uint2 qb = pk[b * 32 + c];
        float s0a = We[at[a] * 32 + c];
        float s0b = We[at[b] * 32 + c];
        float dR0 = dot8q(d, wr0), dR1 = dot8q(d, wr1), dR2 = dot8q(d, wr2);
        float tc = dR0 * (blo(qa.y) * s0b + blo(qb.y) * s0a)
                 + dR1 * (bhi(qa.y) * blo(qb.x) + bhi(qb.y) * blo(qa.x))
                 + dR2 * g2c * (bhi(qa.x) + bhi(qb.x));
#pragma unroll
        for (int o = 1; o <= 16; o <<= 1) tc += __shfl_xor(tc, o, 32);
        float4 uv = unit[k];
        if (c < 3) {
            float uc = (c == 0) ? uv.x : (c == 1) ? uv.y : uv.z;
            atomicAdd(&out[8 + a * 3 + c], tc * uc);
        } else if (c < 6) {
            int d3 = c - 3;
            float uc = (d3 == 0) ? uv.x : (d3 == 1) ? uv.y : uv.z;
            atomicAdd(&out[8 + b * 3 + d3], -tc * uc);
        }
    }
}

extern "C" void kernel_launch(void* const* d_in, const int* in_sizes, int n_in,
                              void* d_out, int out_size, void* d_ws, size_t ws_size,
                              hipStream_t stream)
{
    const float* pos     = (const float*)d_in[0];
    const int*   eidx    = (const int*)  d_in[1];
    const float* cell    = (const float*)d_in[2];
    const int*   at      = (const int*)  d_in[3];
    const float* W_embed = (const float*)d_in[4];
    const float* W_rad   = (const float*)d_in[5];
    const float* W_mix   = (const float*)d_in[6];
    const float* w_out   = (const float*)d_in[7];
    const int*   co      = (const int*)  d_in[8];

    char* p = (char*)d_ws;
    auto carve = [&](size_t bytes) -> char* {
        char* r = p;
        p += (bytes + 255) & ~(size_t)255;
        return r;
    };
    uint4*          dbq    = (uint4*)          carve((size_t)FE * 16);
    float4*         unit   = (float4*)         carve((size_t)FE * 16);
    unsigned short* s1q    = (unsigned short*) carve((size_t)FN * 32 * 2);
    unsigned short* s2q    = (unsigned short*) carve((size_t)FN * 32 * 2);
    unsigned short* ba1q   = (unsigned short*) carve((size_t)FN * 32 * 2);
    float*          barS2  = (float*)          carve((size_t)FN * 32 * 4);
    uint2*          pk     = (uint2*)          carve((size_t)FN * 32 * 8);
    float*          g2     = (float*)          carve(32 * 4);
    int*            cnt    = (int*)            carve((size_t)FN * 4);
    int*            nbq    = (int*)            carve((size_t)FN * CAP * 4);
    uint4*          binc   = (uint4*)          carve((size_t)FN * CAP * 16);

    hipMemsetAsync(cnt, 0, (size_t)FN * 4, stream);
    hipMemsetAsync(d_out, 0, (size_t)(8 + FN * 3) * 4, stream);  // energy + force accumulators

    k_edges<<<FE / 256, 256, 0, stream>>>(pos, eidx, cell, co, at, dbq, unit, cnt, nbq, binc);
    k_g2<<<1, 32, 0, stream>>>(w_out, W_mix + 2 * 1024, g2);

    // forward
    k_L<true><<<FN / 4, 256, 0, stream>>>(nullptr, W_embed, s1q, cnt, nbq, binc,
                                          W_rad + 0 * 1024, W_mix + 0 * 1024, at);
    k_L<false><<<FN / 4, 256, 0, stream>>>(s1q, W_embed, s2q, cnt, nbq, binc,
                                           W_rad + 1 * 1024, W_mix + 1 * 1024, at);
    // layer 2 + energy + barS2 + barA1
    k_L2E<<<FN / 4, 256, 0, stream>>>(s2q, cnt, nbq, binc, W_rad + 2 * 1024,
                                      W_mix + 1 * 1024, w_out, g2, barS2, ba1q, (float*)d_out);
    // backward l=1 + barA0 + pack
    k_B1F<<<FN / 4, 256, 0, stream>>>(ba1q, barS2, s1q, s2q, cnt, nbq, binc,
                                      W_rad + 1 * 1024, W_mix + 0 * 1024, pk);
    // forces (edge-parallel, atomic accumulation)
    k_force_e<<<FE / (8 * EPG), 256, 0, stream>>>(pk, g2, dbq, unit, eidx, at, W_embed, W_rad, (float*)d_out);
}